// Round 2
// baseline (1911.272 us; speedup 1.0000x reference)
//
#include <hip/hip_runtime.h>
#include <hip/hip_bf16.h>

#define DIMC 768
#define NH 12
#define HD 64
#define BB 4
#define NN 1024
#define BHT 48          // BB*NH
#define QKVC 2304       // 3*DIM

#define SZ_QKV (4096 * 2304)      // qkv activations, fp32
#define SZ_AO  (4096 * 768)       // attention output (B,N,C), fp32
#define SZ_A1  (1024 * 1024)      // one head's A (or M) matrix

// ---------------------------------------------------------------------------
// Generic C = A @ B^T + bias.  A: (M,K) row-major, B: (N,K) row-major,
// C: (M,N). 64x64 tile, 256 threads, 4x4 micro-tile, K-tile 16.
// ---------------------------------------------------------------------------
__global__ __launch_bounds__(256) void gemm_bias_abt(
    int M, int Nout, int K,
    const float* __restrict__ A, const float* __restrict__ Bm,
    const float* __restrict__ bias, float* __restrict__ C)
{
    __shared__ float As[16][64];   // [k][i]
    __shared__ float Bs[16][64];   // [k][j]
    const int tid = threadIdx.x;
    const int tx = tid & 15, ty = tid >> 4;
    const int j0 = blockIdx.x * 64, i0 = blockIdx.y * 64;

    float acc[4][4] = {};
    const int il = tid >> 2;            // 0..63
    const int kl = (tid & 3) << 2;      // 0,4,8,12

    for (int k0 = 0; k0 < K; k0 += 16) {
        float4 a4 = *(const float4*)&A[(size_t)(i0 + il) * K + k0 + kl];
        float4 b4 = *(const float4*)&Bm[(size_t)(j0 + il) * K + k0 + kl];
        As[kl + 0][il] = a4.x; As[kl + 1][il] = a4.y;
        As[kl + 2][il] = a4.z; As[kl + 3][il] = a4.w;
        Bs[kl + 0][il] = b4.x; Bs[kl + 1][il] = b4.y;
        Bs[kl + 2][il] = b4.z; Bs[kl + 3][il] = b4.w;
        __syncthreads();
#pragma unroll
        for (int kk = 0; kk < 16; ++kk) {
            float4 av = *(const float4*)&As[kk][ty * 4];
            float4 bv = *(const float4*)&Bs[kk][tx * 4];
            float ar[4] = {av.x, av.y, av.z, av.w};
            float br[4] = {bv.x, bv.y, bv.z, bv.w};
#pragma unroll
            for (int r = 0; r < 4; ++r)
#pragma unroll
                for (int c = 0; c < 4; ++c)
                    acc[r][c] = fmaf(ar[r], br[c], acc[r][c]);
        }
        __syncthreads();
    }

    float4 bv = *(const float4*)&bias[j0 + tx * 4];
#pragma unroll
    for (int r = 0; r < 4; ++r) {
        float4 o;
        o.x = acc[r][0] + bv.x; o.y = acc[r][1] + bv.y;
        o.z = acc[r][2] + bv.z; o.w = acc[r][3] + bv.w;
        *(float4*)&C[(size_t)(i0 + ty * 4 + r) * Nout + j0 + tx * 4] = o;
    }
}

// ---------------------------------------------------------------------------
// S = scale * q @ k^T per head.  q,k live inside qkv buffer (stride 2304).
// grid: (16 jt, 16 it, CH chunk-local heads); global bh = h0 + z.
// ---------------------------------------------------------------------------
__global__ __launch_bounds__(256) void qk_gemm(
    const float* __restrict__ qkv, float* __restrict__ Abuf, int h0)
{
    __shared__ float Qs[64][64];   // [d][i]  (scale folded in)
    __shared__ float Ks[64][64];   // [d][j]
    const int tid = threadIdx.x;
    const int tx = tid & 15, ty = tid >> 4;
    const int j0 = blockIdx.x * 64, i0 = blockIdx.y * 64;
    const int bhl = blockIdx.z;
    const int bh = h0 + bhl;
    const int b = bh / NH, h = bh % NH;

    const float* qbase = qkv + (size_t)(b * NN) * QKVC + h * HD;
    const float* kbase = qbase + DIMC;

    const int rr = tid >> 2;           // 0..63 (row)
    const int d0 = (tid & 3) * 16;     // 0,16,32,48
#pragma unroll
    for (int w = 0; w < 4; ++w) {
        float4 q4 = *(const float4*)&qbase[(size_t)(i0 + rr) * QKVC + d0 + w * 4];
        float4 k4 = *(const float4*)&kbase[(size_t)(j0 + rr) * QKVC + d0 + w * 4];
        Qs[d0 + w * 4 + 0][rr] = q4.x * 0.125f;
        Qs[d0 + w * 4 + 1][rr] = q4.y * 0.125f;
        Qs[d0 + w * 4 + 2][rr] = q4.z * 0.125f;
        Qs[d0 + w * 4 + 3][rr] = q4.w * 0.125f;
        Ks[d0 + w * 4 + 0][rr] = k4.x;
        Ks[d0 + w * 4 + 1][rr] = k4.y;
        Ks[d0 + w * 4 + 2][rr] = k4.z;
        Ks[d0 + w * 4 + 3][rr] = k4.w;
    }
    __syncthreads();

    float acc[4][4] = {};
#pragma unroll 16
    for (int kk = 0; kk < 64; ++kk) {
        float4 av = *(const float4*)&Qs[kk][ty * 4];
        float4 bv = *(const float4*)&Ks[kk][tx * 4];
        float ar[4] = {av.x, av.y, av.z, av.w};
        float br[4] = {bv.x, bv.y, bv.z, bv.w};
#pragma unroll
        for (int r = 0; r < 4; ++r)
#pragma unroll
            for (int c = 0; c < 4; ++c)
                acc[r][c] = fmaf(ar[r], br[c], acc[r][c]);
    }

    float* Ch = Abuf + (size_t)bhl * NN * NN;
#pragma unroll
    for (int r = 0; r < 4; ++r) {
        float4 o;
        o.x = acc[r][0]; o.y = acc[r][1]; o.z = acc[r][2]; o.w = acc[r][3];
        *(float4*)&Ch[(size_t)(i0 + ty * 4 + r) * NN + j0 + tx * 4] = o;
    }
}

// ---------------------------------------------------------------------------
// In-place row softmax over 1024 cols. grid: CH*1024 blocks of 256.
// ---------------------------------------------------------------------------
__global__ __launch_bounds__(256) void softmax_inplace(float* __restrict__ Abuf)
{
    const int row = blockIdx.x;        // bhl*1024 + i
    float* p = Abuf + (size_t)row * NN;
    const int tid = threadIdx.x;
    __shared__ float redm[4], reds[4];

    float4 v = *(float4*)&p[tid * 4];
    float m = fmaxf(fmaxf(v.x, v.y), fmaxf(v.z, v.w));
#pragma unroll
    for (int off = 32; off >= 1; off >>= 1) m = fmaxf(m, __shfl_xor(m, off));
    if ((tid & 63) == 0) redm[tid >> 6] = m;
    __syncthreads();
    m = fmaxf(fmaxf(redm[0], redm[1]), fmaxf(redm[2], redm[3]));

    v.x = expf(v.x - m); v.y = expf(v.y - m);
    v.z = expf(v.z - m); v.w = expf(v.w - m);
    float s = v.x + v.y + v.z + v.w;
#pragma unroll
    for (int off = 32; off >= 1; off >>= 1) s += __shfl_xor(s, off);
    if ((tid & 63) == 0) reds[tid >> 6] = s;
    __syncthreads();
    s = reds[0] + reds[1] + reds[2] + reds[3];

    const float inv = 1.0f / s;
    v.x *= inv; v.y *= inv; v.z *= inv; v.w *= inv;
    *(float4*)&p[tid * 4] = v;
}

// ---------------------------------------------------------------------------
// M = relu(delta*I + (gamma-6*lamb)*A + 7*lamb*(A@A)); atomic row sums.
// grid: (16 jt, 16 it, CH), 64x64 tile, K-tile 32.
// ---------------------------------------------------------------------------
__global__ __launch_bounds__(256) void mpow_kernel(
    const float* __restrict__ Abuf, float* __restrict__ Mbuf,
    float* __restrict__ rowsum,
    const float* __restrict__ lamb, const float* __restrict__ gamma,
    const float* __restrict__ delta, int h0)
{
    __shared__ float As[32][64];   // [k][i]
    __shared__ float Bs[32][64];   // [k][j]
    const int tid = threadIdx.x;
    const int tx = tid & 15, ty = tid >> 4;
    const int j0 = blockIdx.x * 64, i0 = blockIdx.y * 64;
    const int bhl = blockIdx.z;
    const int h = (h0 + bhl) % NH;
    const float* Ah = Abuf + (size_t)bhl * NN * NN;

    float acc[4][4] = {};
    const int il = tid >> 2;            // 0..63
    const int klA = (tid & 3) * 8;      // 0,8,16,24
    const int kb = tid >> 3;            // 0..31
    const int jb = (tid & 7) * 8;       // 0..56

    for (int k0 = 0; k0 < NN; k0 += 32) {
        const float* ap = &Ah[(size_t)(i0 + il) * NN + k0 + klA];
        float4 a0 = *(const float4*)ap;
        float4 a1 = *(const float4*)(ap + 4);
        As[klA + 0][il] = a0.x; As[klA + 1][il] = a0.y;
        As[klA + 2][il] = a0.z; As[klA + 3][il] = a0.w;
        As[klA + 4][il] = a1.x; As[klA + 5][il] = a1.y;
        As[klA + 6][il] = a1.z; As[klA + 7][il] = a1.w;
        const float* bp = &Ah[(size_t)(k0 + kb) * NN + j0 + jb];
        *(float4*)&Bs[kb][jb] = *(const float4*)bp;
        *(float4*)&Bs[kb][jb + 4] = *(const float4*)(bp + 4);
        __syncthreads();
#pragma unroll
        for (int kk = 0; kk < 32; ++kk) {
            float4 av = *(const float4*)&As[kk][ty * 4];
            float4 bv = *(const float4*)&Bs[kk][tx * 4];
            float ar[4] = {av.x, av.y, av.z, av.w};
            float br[4] = {bv.x, bv.y, bv.z, bv.w};
#pragma unroll
            for (int r = 0; r < 4; ++r)
#pragma unroll
                for (int c = 0; c < 4; ++c)
                    acc[r][c] = fmaf(ar[r], br[c], acc[r][c]);
        }
        __syncthreads();
    }

    const float lam = lamb[h];
    const float c1 = gamma[h] - 6.0f * lam;
    const float c2 = 7.0f * lam;
    const float del = delta[h];

#pragma unroll
    for (int r = 0; r < 4; ++r) {
        const int i = i0 + ty * 4 + r;
        const int j = j0 + tx * 4;
        float4 av = *(const float4*)&Ah[(size_t)i * NN + j];
        float4 mv;
        mv.x = fmaxf(c2 * acc[r][0] + c1 * av.x + ((j + 0) == i ? del : 0.0f), 0.0f);
        mv.y = fmaxf(c2 * acc[r][1] + c1 * av.y + ((j + 1) == i ? del : 0.0f), 0.0f);
        mv.z = fmaxf(c2 * acc[r][2] + c1 * av.z + ((j + 2) == i ? del : 0.0f), 0.0f);
        mv.w = fmaxf(c2 * acc[r][3] + c1 * av.w + ((j + 3) == i ? del : 0.0f), 0.0f);
        *(float4*)&Mbuf[(size_t)bhl * NN * NN + (size_t)i * NN + j] = mv;
        float rp = mv.x + mv.y + mv.z + mv.w;
#pragma unroll
        for (int off = 1; off < 16; off <<= 1) rp += __shfl_xor(rp, off);
        if (tx == 0) atomicAdd(&rowsum[bhl * NN + i], rp);
    }
}

// ---------------------------------------------------------------------------
// out = (M / (rowsum+eps)) @ v, written to (B, N, 768) layout.
// grid: (16 it, CH). tile 64 rows x 64 cols(d). K-tile 32.
// ---------------------------------------------------------------------------
__global__ __launch_bounds__(256) void pv_kernel(
    const float* __restrict__ Mbuf, const float* __restrict__ rowsum,
    const float* __restrict__ qkv, float* __restrict__ ao, int h0)
{
    __shared__ float Ms[32][64];   // [k][i]
    __shared__ float Vs[32][64];   // [k][d]
    const int tid = threadIdx.x;
    const int tx = tid & 15, ty = tid >> 4;
    const int i0 = blockIdx.x * 64;
    const int bhl = blockIdx.y;
    const int bh = h0 + bhl;
    const int b = bh / NH, h = bh % NH;
    const float* Mh = Mbuf + (size_t)bhl * NN * NN;
    const float* vbase = qkv + (size_t)(b * NN) * QKVC + 2 * DIMC + h * HD;

    float acc[4][4] = {};
    const int il = tid >> 2;
    const int klA = (tid & 3) * 8;
    const int kb = tid >> 3;
    const int db = (tid & 7) * 8;

    for (int k0 = 0; k0 < NN; k0 += 32) {
        const float* mp = &Mh[(size_t)(i0 + il) * NN + k0 + klA];
        float4 m0 = *(const float4*)mp;
        float4 m1 = *(const float4*)(mp + 4);
        Ms[klA + 0][il] = m0.x; Ms[klA + 1][il] = m0.y;
        Ms[klA + 2][il] = m0.z; Ms[klA + 3][il] = m0.w;
        Ms[klA + 4][il] = m1.x; Ms[klA + 5][il] = m1.y;
        Ms[klA + 6][il] = m1.z; Ms[klA + 7][il] = m1.w;
        const float* vp = &vbase[(size_t)(k0 + kb) * QKVC + db];
        *(float4*)&Vs[kb][db] = *(const float4*)vp;
        *(float4*)&Vs[kb][db + 4] = *(const float4*)(vp + 4);
        __syncthreads();
#pragma unroll
        for (int kk = 0; kk < 32; ++kk) {
            float4 av = *(const float4*)&Ms[kk][ty * 4];
            float4 bv = *(const float4*)&Vs[kk][tx * 4];
            float ar[4] = {av.x, av.y, av.z, av.w};
            float br[4] = {bv.x, bv.y, bv.z, bv.w};
#pragma unroll
            for (int r = 0; r < 4; ++r)
#pragma unroll
                for (int c = 0; c < 4; ++c)
                    acc[r][c] = fmaf(ar[r], br[c], acc[r][c]);
        }
        __syncthreads();
    }

#pragma unroll
    for (int r = 0; r < 4; ++r) {
        const int i = i0 + ty * 4 + r;
        const float inv = 1.0f / (rowsum[bhl * NN + i] + 1e-9f);
        float4 o;
        o.x = acc[r][0] * inv; o.y = acc[r][1] * inv;
        o.z = acc[r][2] * inv; o.w = acc[r][3] * inv;
        *(float4*)&ao[(size_t)(b * NN + i) * DIMC + h * HD + tx * 4] = o;
    }
}

// ---------------------------------------------------------------------------
extern "C" void kernel_launch(void* const* d_in, const int* in_sizes, int n_in,
                              void* d_out, int out_size, void* d_ws, size_t ws_size,
                              hipStream_t stream)
{
    const float* x      = (const float*)d_in[0];
    const float* qkv_w  = (const float*)d_in[1];
    const float* qkv_b  = (const float*)d_in[2];
    const float* proj_w = (const float*)d_in[3];
    const float* proj_b = (const float*)d_in[4];
    const float* lamb   = (const float*)d_in[5];
    const float* gamma  = (const float*)d_in[6];
    const float* delta  = (const float*)d_in[7];

    float* ws   = (float*)d_ws;
    float* qkvb = ws;                       // SZ_QKV
    float* ao   = qkvb + SZ_QKV;            // SZ_AO

    // Choose largest head-chunk CH (divisor of 48) that fits ws_size.
    const size_t availf = ws_size / sizeof(float);
    const size_t fixedf = (size_t)SZ_QKV + (size_t)SZ_AO;
    static const int choices[] = {48, 24, 16, 12, 8, 6, 4, 3, 2, 1};
    int CH = 1;
    for (int ci = 0; ci < 10; ++ci) {
        int c = choices[ci];
        size_t need = fixedf + (size_t)c * (2 * (size_t)SZ_A1 + NN);
        if (need <= availf) { CH = c; break; }
    }

    float* Abuf = ao + SZ_AO;                        // CH * SZ_A1
    float* Mbuf = Abuf + (size_t)CH * SZ_A1;         // CH * SZ_A1
    float* rs   = Mbuf + (size_t)CH * SZ_A1;         // CH * NN

    // 1) qkv = x @ qkv_w^T + qkv_b   (4096 x 2304 x 768)
    gemm_bias_abt<<<dim3(QKVC / 64, 4096 / 64), 256, 0, stream>>>(
        4096, QKVC, DIMC, x, qkv_w, qkv_b, qkvb);

    // 2..5) per chunk of heads
    for (int h0 = 0; h0 < BHT; h0 += CH) {
        qk_gemm<<<dim3(16, 16, CH), 256, 0, stream>>>(qkvb, Abuf, h0);
        softmax_inplace<<<dim3(CH * NN), 256, 0, stream>>>(Abuf);
        hipMemsetAsync(rs, 0, (size_t)CH * NN * sizeof(float), stream);
        mpow_kernel<<<dim3(16, 16, CH), 256, 0, stream>>>(
            Abuf, Mbuf, rs, lamb, gamma, delta, h0);
        pv_kernel<<<dim3(16, CH), 256, 0, stream>>>(Mbuf, rs, qkvb, ao, h0);
    }

    // 6) final = ao @ proj_w^T + proj_b
    gemm_bias_abt<<<dim3(DIMC / 64, 4096 / 64), 256, 0, stream>>>(
        4096, DIMC, DIMC, ao, proj_w, proj_b, (float*)d_out);
}

// Round 3
// 900.399 us; speedup vs baseline: 2.1227x; 2.1227x over previous
//
#include <hip/hip_runtime.h>
#include <hip/hip_bf16.h>

#define DIMC 768
#define NH 12
#define HD 64
#define BB 4
#define NN 1024
#define BHT 48          // BB*NH
#define QKVC 2304       // 3*DIM

#define SZ_QKV (4096 * 2304)      // qkv activations, fp32
#define SZ_AO  (4096 * 768)       // attention output (B,N,C), fp32
#define SZ_A1  (1024 * 1024)      // one head's NxN matrix (element count)

typedef unsigned short u16;
typedef __attribute__((ext_vector_type(8))) unsigned short u16x8;
typedef __attribute__((ext_vector_type(8))) short s16x8;
typedef __attribute__((ext_vector_type(4))) float f32x4;

__device__ __forceinline__ u16 f2bf(float f) {
    unsigned u = __float_as_uint(f);
    return (u16)((u + 0x7FFF + ((u >> 16) & 1)) >> 16);   // RNE
}
__device__ __forceinline__ float bf2f(u16 v) {
    return __uint_as_float(((unsigned)v) << 16);
}

// ---------------------------------------------------------------------------
// Generic C = A @ B^T + bias (fp32). 64x64 tile, 256 threads, 4x4 micro.
// ---------------------------------------------------------------------------
__global__ __launch_bounds__(256) void gemm_bias_abt(
    int M, int Nout, int K,
    const float* __restrict__ A, const float* __restrict__ Bm,
    const float* __restrict__ bias, float* __restrict__ C)
{
    __shared__ float As[16][64];
    __shared__ float Bs[16][64];
    const int tid = threadIdx.x;
    const int tx = tid & 15, ty = tid >> 4;
    const int j0 = blockIdx.x * 64, i0 = blockIdx.y * 64;

    float acc[4][4] = {};
    const int il = tid >> 2;
    const int kl = (tid & 3) << 2;

    for (int k0 = 0; k0 < K; k0 += 16) {
        float4 a4 = *(const float4*)&A[(size_t)(i0 + il) * K + k0 + kl];
        float4 b4 = *(const float4*)&Bm[(size_t)(j0 + il) * K + k0 + kl];
        As[kl + 0][il] = a4.x; As[kl + 1][il] = a4.y;
        As[kl + 2][il] = a4.z; As[kl + 3][il] = a4.w;
        Bs[kl + 0][il] = b4.x; Bs[kl + 1][il] = b4.y;
        Bs[kl + 2][il] = b4.z; Bs[kl + 3][il] = b4.w;
        __syncthreads();
#pragma unroll
        for (int kk = 0; kk < 16; ++kk) {
            float4 av = *(const float4*)&As[kk][ty * 4];
            float4 bv = *(const float4*)&Bs[kk][tx * 4];
            float ar[4] = {av.x, av.y, av.z, av.w};
            float br[4] = {bv.x, bv.y, bv.z, bv.w};
#pragma unroll
            for (int r = 0; r < 4; ++r)
#pragma unroll
                for (int c = 0; c < 4; ++c)
                    acc[r][c] = fmaf(ar[r], br[c], acc[r][c]);
        }
        __syncthreads();
    }

    float4 bv = *(const float4*)&bias[j0 + tx * 4];
#pragma unroll
    for (int r = 0; r < 4; ++r) {
        float4 o;
        o.x = acc[r][0] + bv.x; o.y = acc[r][1] + bv.y;
        o.z = acc[r][2] + bv.z; o.w = acc[r][3] + bv.w;
        *(float4*)&C[(size_t)(i0 + ty * 4 + r) * Nout + j0 + tx * 4] = o;
    }
}

// ---------------------------------------------------------------------------
// S = scale * q @ k^T per head (fp32). grid: (16, 16, CH).
// ---------------------------------------------------------------------------
__global__ __launch_bounds__(256) void qk_gemm(
    const float* __restrict__ qkv, float* __restrict__ Abuf, int h0)
{
    __shared__ float Qs[64][64];
    __shared__ float Ks[64][64];
    const int tid = threadIdx.x;
    const int tx = tid & 15, ty = tid >> 4;
    const int j0 = blockIdx.x * 64, i0 = blockIdx.y * 64;
    const int bhl = blockIdx.z;
    const int bh = h0 + bhl;
    const int b = bh / NH, h = bh % NH;

    const float* qbase = qkv + (size_t)(b * NN) * QKVC + h * HD;
    const float* kbase = qbase + DIMC;

    const int rr = tid >> 2;
    const int d0 = (tid & 3) * 16;
#pragma unroll
    for (int w = 0; w < 4; ++w) {
        float4 q4 = *(const float4*)&qbase[(size_t)(i0 + rr) * QKVC + d0 + w * 4];
        float4 k4 = *(const float4*)&kbase[(size_t)(j0 + rr) * QKVC + d0 + w * 4];
        Qs[d0 + w * 4 + 0][rr] = q4.x * 0.125f;
        Qs[d0 + w * 4 + 1][rr] = q4.y * 0.125f;
        Qs[d0 + w * 4 + 2][rr] = q4.z * 0.125f;
        Qs[d0 + w * 4 + 3][rr] = q4.w * 0.125f;
        Ks[d0 + w * 4 + 0][rr] = k4.x;
        Ks[d0 + w * 4 + 1][rr] = k4.y;
        Ks[d0 + w * 4 + 2][rr] = k4.z;
        Ks[d0 + w * 4 + 3][rr] = k4.w;
    }
    __syncthreads();

    float acc[4][4] = {};
#pragma unroll 16
    for (int kk = 0; kk < 64; ++kk) {
        float4 av = *(const float4*)&Qs[kk][ty * 4];
        float4 bv = *(const float4*)&Ks[kk][tx * 4];
        float ar[4] = {av.x, av.y, av.z, av.w};
        float br[4] = {bv.x, bv.y, bv.z, bv.w};
#pragma unroll
        for (int r = 0; r < 4; ++r)
#pragma unroll
            for (int c = 0; c < 4; ++c)
                acc[r][c] = fmaf(ar[r], br[c], acc[r][c]);
    }

    float* Ch = Abuf + (size_t)bhl * NN * NN;
#pragma unroll
    for (int r = 0; r < 4; ++r) {
        float4 o;
        o.x = acc[r][0]; o.y = acc[r][1]; o.z = acc[r][2]; o.w = acc[r][3];
        *(float4*)&Ch[(size_t)(i0 + ty * 4 + r) * NN + j0 + tx * 4] = o;
    }
}

// ---------------------------------------------------------------------------
// In-place row softmax over 1024 cols (fp32).
// ---------------------------------------------------------------------------
__global__ __launch_bounds__(256) void softmax_inplace(float* __restrict__ Abuf)
{
    const int row = blockIdx.x;
    float* p = Abuf + (size_t)row * NN;
    const int tid = threadIdx.x;
    __shared__ float redm[4], reds[4];

    float4 v = *(float4*)&p[tid * 4];
    float m = fmaxf(fmaxf(v.x, v.y), fmaxf(v.z, v.w));
#pragma unroll
    for (int off = 32; off >= 1; off >>= 1) m = fmaxf(m, __shfl_xor(m, off));
    if ((tid & 63) == 0) redm[tid >> 6] = m;
    __syncthreads();
    m = fmaxf(fmaxf(redm[0], redm[1]), fmaxf(redm[2], redm[3]));

    v.x = expf(v.x - m); v.y = expf(v.y - m);
    v.z = expf(v.z - m); v.w = expf(v.w - m);
    float s = v.x + v.y + v.z + v.w;
#pragma unroll
    for (int off = 32; off >= 1; off >>= 1) s += __shfl_xor(s, off);
    if ((tid & 63) == 0) reds[tid >> 6] = s;
    __syncthreads();
    s = reds[0] + reds[1] + reds[2] + reds[3];

    const float inv = 1.0f / s;
    v.x *= inv; v.y *= inv; v.z *= inv; v.w *= inv;
    *(float4*)&p[tid * 4] = v;
}

// ---------------------------------------------------------------------------
// At_bf16[j][i] = bf16(A_f32[i][j]) per head. 64x64 tiles. grid (16,16,CH).
// ---------------------------------------------------------------------------
__global__ __launch_bounds__(256) void transpose_f2b(
    const float* __restrict__ Af, u16* __restrict__ Atb)
{
    __shared__ u16 t[64][65];
    const int tid = threadIdx.x;
    const int j0 = blockIdx.x * 64, i0 = blockIdx.y * 64;
    const int bz = blockIdx.z;
    const float* src = Af + (size_t)bz * NN * NN;
    u16* dst = Atb + (size_t)bz * NN * NN;

    const int row = tid >> 2;          // 0..63
    const int ch = tid & 3;            // 16-col chunk
    const float* sp = &src[(size_t)(i0 + row) * NN + j0 + ch * 16];
#pragma unroll
    for (int e = 0; e < 16; e += 4) {
        float4 v = *(const float4*)(sp + e);
        t[row][ch * 16 + e + 0] = f2bf(v.x);
        t[row][ch * 16 + e + 1] = f2bf(v.y);
        t[row][ch * 16 + e + 2] = f2bf(v.z);
        t[row][ch * 16 + e + 3] = f2bf(v.w);
    }
    __syncthreads();

    const int oj = tid >> 2, och = tid & 3;
    u16x8 o0, o1;
#pragma unroll
    for (int e = 0; e < 8; ++e) o0[e] = t[och * 16 + e][oj];
#pragma unroll
    for (int e = 0; e < 8; ++e) o1[e] = t[och * 16 + 8 + e][oj];
    u16* dp = &dst[(size_t)(j0 + oj) * NN + i0 + och * 16];
    *(u16x8*)dp = o0;
    *(u16x8*)(dp + 8) = o1;
}

// ---------------------------------------------------------------------------
// MFMA mpow: P = A@A via bf16 MFMA (A row-major from fp32 A, A^T bf16);
// M = relu(delta*I + c1*A + c2*P) stored bf16; rowsum atomics.
// 128x128 tile, 4 waves, BK=32. grid (8, 8, CH).
// ---------------------------------------------------------------------------
__global__ __launch_bounds__(256) void mpow_mfma(
    const float* __restrict__ Af, const u16* __restrict__ Atb,
    u16* __restrict__ Mb, float* __restrict__ rowsum,
    const float* __restrict__ lamb, const float* __restrict__ gamma,
    const float* __restrict__ delta, int h0)
{
    __shared__ u16 Asl[128 * 32];   // [row][k] linear, 64B rows
    __shared__ u16 Bsl[128 * 32];
    const int tid = threadIdx.x;
    const int j0 = blockIdx.x * 128, i0 = blockIdx.y * 128;
    const int bz = blockIdx.z;
    const int h = (h0 + bz) % NH;
    const float* Ah = Af + (size_t)bz * NN * NN;
    const u16* Ath = Atb + (size_t)bz * NN * NN;

    const int srow = tid >> 2;          // staging row 0..63 (+64 on pass 1)
    const int skb = tid & 3;            // 8-elem k chunk
    const int w = tid >> 6, l = tid & 63;
    const int wr = w >> 1, wc = w & 1;
    const int l15 = l & 15, kb4 = l >> 4;

    f32x4 acc[4][4];
    const f32x4 zero = {0.f, 0.f, 0.f, 0.f};
#pragma unroll
    for (int a = 0; a < 4; ++a)
#pragma unroll
        for (int b = 0; b < 4; ++b) acc[a][b] = zero;

    for (int k0 = 0; k0 < NN; k0 += 32) {
#pragma unroll
        for (int p = 0; p < 2; ++p) {
            const int r = p * 64 + srow;
            const float* ap = &Ah[(size_t)(i0 + r) * NN + k0 + skb * 8];
            float4 a0 = *(const float4*)ap;
            float4 a1 = *(const float4*)(ap + 4);
            u16x8 av;
            av[0] = f2bf(a0.x); av[1] = f2bf(a0.y);
            av[2] = f2bf(a0.z); av[3] = f2bf(a0.w);
            av[4] = f2bf(a1.x); av[5] = f2bf(a1.y);
            av[6] = f2bf(a1.z); av[7] = f2bf(a1.w);
            *(u16x8*)&Asl[r * 32 + skb * 8] = av;
            u16x8 bv = *(const u16x8*)&Ath[(size_t)(j0 + r) * NN + k0 + skb * 8];
            *(u16x8*)&Bsl[r * 32 + skb * 8] = bv;
        }
        __syncthreads();

        s16x8 af[4], bf[4];
#pragma unroll
        for (int f = 0; f < 4; ++f) {
            af[f] = *(const s16x8*)&Asl[(wr * 64 + f * 16 + l15) * 32 + kb4 * 8];
            bf[f] = *(const s16x8*)&Bsl[(wc * 64 + f * 16 + l15) * 32 + kb4 * 8];
        }
#pragma unroll
        for (int fr = 0; fr < 4; ++fr)
#pragma unroll
            for (int fc = 0; fc < 4; ++fc)
                acc[fr][fc] = __builtin_amdgcn_mfma_f32_16x16x32_bf16(
                    af[fr], bf[fc], acc[fr][fc], 0, 0, 0);
        __syncthreads();
    }

    const float lam = lamb[h];
    const float c1 = gamma[h] - 6.0f * lam;
    const float c2 = 7.0f * lam;
    const float del = delta[h];
    u16* Mh = Mb + (size_t)bz * NN * NN;
    float* rsh = rowsum + bz * NN;

#pragma unroll
    for (int fr = 0; fr < 4; ++fr) {
#pragma unroll
        for (int r = 0; r < 4; ++r) {
            const int gi = i0 + wr * 64 + fr * 16 + kb4 * 4 + r;
            float rowacc = 0.f;
#pragma unroll
            for (int fc = 0; fc < 4; ++fc) {
                const int gj = j0 + wc * 64 + fc * 16 + l15;
                const float a = Ah[(size_t)gi * NN + gj];
                float m = c2 * acc[fr][fc][r] + c1 * a + (gi == gj ? del : 0.f);
                m = fmaxf(m, 0.f);
                Mh[(size_t)gi * NN + gj] = f2bf(m);
                rowacc += m;
            }
            rowacc += __shfl_xor(rowacc, 1);
            rowacc += __shfl_xor(rowacc, 2);
            rowacc += __shfl_xor(rowacc, 4);
            rowacc += __shfl_xor(rowacc, 8);
            if (l15 == 0) atomicAdd(&rsh[gi], rowacc);
        }
    }
}

// ---------------------------------------------------------------------------
// out = (Mb / (rowsum+eps)) @ v  -> (B, N, 768). M is bf16 now.
// ---------------------------------------------------------------------------
__global__ __launch_bounds__(256) void pv_kernel(
    const u16* __restrict__ Mb, const float* __restrict__ rowsum,
    const float* __restrict__ qkv, float* __restrict__ ao, int h0)
{
    __shared__ float Ms[32][64];
    __shared__ float Vs[32][64];
    const int tid = threadIdx.x;
    const int tx = tid & 15, ty = tid >> 4;
    const int i0 = blockIdx.x * 64;
    const int bhl = blockIdx.y;
    const int bh = h0 + bhl;
    const int b = bh / NH, h = bh % NH;
    const u16* Mh = Mb + (size_t)bhl * NN * NN;
    const float* vbase = qkv + (size_t)(b * NN) * QKVC + 2 * DIMC + h * HD;

    float acc[4][4] = {};
    const int il = tid >> 2;
    const int klA = (tid & 3) * 8;
    const int kb = tid >> 3;
    const int db = (tid & 7) * 8;

    for (int k0 = 0; k0 < NN; k0 += 32) {
        u16x8 mu = *(const u16x8*)&Mh[(size_t)(i0 + il) * NN + k0 + klA];
#pragma unroll
        for (int e = 0; e < 8; ++e) Ms[klA + e][il] = bf2f(mu[e]);
        const float* vp = &vbase[(size_t)(k0 + kb) * QKVC + db];
        *(float4*)&Vs[kb][db] = *(const float4*)vp;
        *(float4*)&Vs[kb][db + 4] = *(const float4*)(vp + 4);
        __syncthreads();
#pragma unroll
        for (int kk = 0; kk < 32; ++kk) {
            float4 av = *(const float4*)&Ms[kk][ty * 4];
            float4 bv = *(const float4*)&Vs[kk][tx * 4];
            float ar[4] = {av.x, av.y, av.z, av.w};
            float br[4] = {bv.x, bv.y, bv.z, bv.w};
#pragma unroll
            for (int r = 0; r < 4; ++r)
#pragma unroll
                for (int c = 0; c < 4; ++c)
                    acc[r][c] = fmaf(ar[r], br[c], acc[r][c]);
        }
        __syncthreads();
    }

#pragma unroll
    for (int r = 0; r < 4; ++r) {
        const int i = i0 + ty * 4 + r;
        const float inv = 1.0f / (rowsum[bhl * NN + i] + 1e-9f);
        float4 o;
        o.x = acc[r][0] * inv; o.y = acc[r][1] * inv;
        o.z = acc[r][2] * inv; o.w = acc[r][3] * inv;
        *(float4*)&ao[(size_t)(b * NN + i) * DIMC + h * HD + tx * 4] = o;
    }
}

// ---------------------------------------------------------------------------
extern "C" void kernel_launch(void* const* d_in, const int* in_sizes, int n_in,
                              void* d_out, int out_size, void* d_ws, size_t ws_size,
                              hipStream_t stream)
{
    const float* x      = (const float*)d_in[0];
    const float* qkv_w  = (const float*)d_in[1];
    const float* qkv_b  = (const float*)d_in[2];
    const float* proj_w = (const float*)d_in[3];
    const float* proj_b = (const float*)d_in[4];
    const float* lamb   = (const float*)d_in[5];
    const float* gamma  = (const float*)d_in[6];
    const float* delta  = (const float*)d_in[7];

    float* ws   = (float*)d_ws;
    float* qkvb = ws;                       // SZ_QKV floats
    float* ao   = qkvb + SZ_QKV;            // SZ_AO floats

    // per-head float-equivalents: A fp32 (1M) + Atb bf16 (0.5M) + Mb bf16 (0.5M) + rs
    const size_t availf = ws_size / sizeof(float);
    const size_t fixedf = (size_t)SZ_QKV + (size_t)SZ_AO;
    const size_t perh = (size_t)SZ_A1 + SZ_A1 / 2 + SZ_A1 / 2 + NN;
    static const int choices[] = {48, 24, 16, 12, 8, 6, 4, 3, 2, 1};
    int CH = 1;
    for (int ci = 0; ci < 10; ++ci) {
        int c = choices[ci];
        if (fixedf + (size_t)c * perh <= availf) { CH = c; break; }
    }

    float* Abuf = ao + SZ_AO;                              // CH * 1M fp32
    u16*   Atb  = (u16*)(Abuf + (size_t)CH * SZ_A1);       // CH * 1M u16
    u16*   Mb   = Atb + (size_t)CH * SZ_A1;                // CH * 1M u16
    float* rs   = (float*)(Mb + (size_t)CH * SZ_A1);       // CH * NN fp32

    // 1) qkv = x @ qkv_w^T + qkv_b
    gemm_bias_abt<<<dim3(QKVC / 64, 4096 / 64), 256, 0, stream>>>(
        4096, QKVC, DIMC, x, qkv_w, qkv_b, qkvb);

    for (int h0 = 0; h0 < BHT; h0 += CH) {
        qk_gemm<<<dim3(16, 16, CH), 256, 0, stream>>>(qkvb, Abuf, h0);
        softmax_inplace<<<dim3(CH * NN), 256, 0, stream>>>(Abuf);
        transpose_f2b<<<dim3(16, 16, CH), 256, 0, stream>>>(Abuf, Atb);
        hipMemsetAsync(rs, 0, (size_t)CH * NN * sizeof(float), stream);
        mpow_mfma<<<dim3(8, 8, CH), 256, 0, stream>>>(
            Abuf, Atb, Mb, rs, lamb, gamma, delta, h0);
        pv_kernel<<<dim3(16, CH), 256, 0, stream>>>(Mb, rs, qkvb, ao, h0);
    }

    // 6) final = ao @ proj_w^T + proj_b
    gemm_bias_abt<<<dim3(DIMC / 64, 4096 / 64), 256, 0, stream>>>(
        4096, DIMC, DIMC, ao, proj_w, proj_b, (float*)d_out);
}

// Round 5
// 610.961 us; speedup vs baseline: 3.1283x; 1.4737x over previous
//
#include <hip/hip_runtime.h>
#include <hip/hip_bf16.h>

#define DIMC 768
#define NH 12
#define HD 64
#define BB 4
#define NN 1024
#define BHT 48          // BB*NH
#define QKVC 2304       // 3*DIM

typedef unsigned short u16;
typedef __attribute__((ext_vector_type(4))) unsigned short u16x4;
typedef __attribute__((ext_vector_type(8))) unsigned short u16x8;
typedef __attribute__((ext_vector_type(8))) short s16x8;
typedef __attribute__((ext_vector_type(4))) float f32x4;

__device__ __forceinline__ u16 f2bf(float f) {
    unsigned u = __float_as_uint(f);
    return (u16)((u + 0x7FFF + ((u >> 16) & 1)) >> 16);   // RNE
}
__device__ __forceinline__ float bf2f(u16 v) {
    return __uint_as_float(((unsigned)v) << 16);
}
struct bfp { u16 h, l; };
__device__ __forceinline__ bfp splitf(float f) {
    bfp r;
    r.h = f2bf(f);
    r.l = f2bf(f - bf2f(r.h));      // exact residual, bf16-rounded
    return r;
}

// ---------------------------------------------------------------------------
// Elementwise split: src fp32 -> (hi, lo) bf16. n multiple of 4.
// ---------------------------------------------------------------------------
__global__ __launch_bounds__(256) void split_f2b(
    const float* __restrict__ src, u16* __restrict__ hi, u16* __restrict__ lo,
    int n4)
{
    int idx = blockIdx.x * 256 + threadIdx.x;
    if (idx >= n4) return;
    float4 v = *(const float4*)&src[idx * 4];
    u16x4 h, l;
    bfp s;
    s = splitf(v.x); h[0] = s.h; l[0] = s.l;
    s = splitf(v.y); h[1] = s.h; l[1] = s.l;
    s = splitf(v.z); h[2] = s.h; l[2] = s.l;
    s = splitf(v.w); h[3] = s.h; l[3] = s.l;
    *(u16x4*)&hi[idx * 4] = h;
    *(u16x4*)&lo[idx * 4] = l;
}

// ---------------------------------------------------------------------------
// Generic split-bf16 GEMM: C = A @ B^T + bias (3-term MFMA, ~fp32 accuracy).
// A:(M,K) B:(N,K) row-major via hi/lo bf16 pairs. 128x128 tile, BK=32.
// grid (N/128, M/128), 256 threads (4 waves, 2x2 wave grid).
// ---------------------------------------------------------------------------
__global__ __launch_bounds__(256) void gemm3_mfma(
    int Mrows, int Nout, int K,
    const u16* __restrict__ Ahp, const u16* __restrict__ Alp,
    const u16* __restrict__ Bhp, const u16* __restrict__ Blp,
    const float* __restrict__ bias, float* __restrict__ C)
{
    __shared__ u16 sAh[128 * 32], sAl[128 * 32], sBh[128 * 32], sBl[128 * 32];
    const int tid = threadIdx.x;
    const int j0 = blockIdx.x * 128, i0 = blockIdx.y * 128;
    const int srow = tid >> 1, shalf = (tid & 1) * 16;
    const int w = tid >> 6, l = tid & 63;
    const int wr = w >> 1, wc = w & 1;
    const int l15 = l & 15, kb4 = l >> 4;

    f32x4 acc[4][4];
    const f32x4 zero = {0.f, 0.f, 0.f, 0.f};
#pragma unroll
    for (int a = 0; a < 4; ++a)
#pragma unroll
        for (int b = 0; b < 4; ++b) acc[a][b] = zero;

    for (int k0 = 0; k0 < K; k0 += 32) {
        const size_t ar = (size_t)(i0 + srow) * K + k0 + shalf;
        const size_t br = (size_t)(j0 + srow) * K + k0 + shalf;
        const int so = srow * 32 + shalf;
        *(u16x8*)&sAh[so]     = *(const u16x8*)&Ahp[ar];
        *(u16x8*)&sAh[so + 8] = *(const u16x8*)&Ahp[ar + 8];
        *(u16x8*)&sAl[so]     = *(const u16x8*)&Alp[ar];
        *(u16x8*)&sAl[so + 8] = *(const u16x8*)&Alp[ar + 8];
        *(u16x8*)&sBh[so]     = *(const u16x8*)&Bhp[br];
        *(u16x8*)&sBh[so + 8] = *(const u16x8*)&Bhp[br + 8];
        *(u16x8*)&sBl[so]     = *(const u16x8*)&Blp[br];
        *(u16x8*)&sBl[so + 8] = *(const u16x8*)&Blp[br + 8];
        __syncthreads();

        s16x8 ah[4], al[4], bh[4], bl[4];
#pragma unroll
        for (int f = 0; f < 4; ++f) {
            const int ao = (wr * 64 + f * 16 + l15) * 32 + kb4 * 8;
            const int bo = (wc * 64 + f * 16 + l15) * 32 + kb4 * 8;
            ah[f] = *(const s16x8*)&sAh[ao];
            al[f] = *(const s16x8*)&sAl[ao];
            bh[f] = *(const s16x8*)&sBh[bo];
            bl[f] = *(const s16x8*)&sBl[bo];
        }
#pragma unroll
        for (int fr = 0; fr < 4; ++fr)
#pragma unroll
            for (int fc = 0; fc < 4; ++fc) {
                acc[fr][fc] = __builtin_amdgcn_mfma_f32_16x16x32_bf16(
                    ah[fr], bh[fc], acc[fr][fc], 0, 0, 0);
                acc[fr][fc] = __builtin_amdgcn_mfma_f32_16x16x32_bf16(
                    ah[fr], bl[fc], acc[fr][fc], 0, 0, 0);
                acc[fr][fc] = __builtin_amdgcn_mfma_f32_16x16x32_bf16(
                    al[fr], bh[fc], acc[fr][fc], 0, 0, 0);
            }
        __syncthreads();
    }

#pragma unroll
    for (int fr = 0; fr < 4; ++fr)
#pragma unroll
        for (int r = 0; r < 4; ++r) {
            const int gi = i0 + wr * 64 + fr * 16 + kb4 * 4 + r;
#pragma unroll
            for (int fc = 0; fc < 4; ++fc) {
                const int gj = j0 + wc * 64 + fc * 16 + l15;
                C[(size_t)gi * Nout + gj] = acc[fr][fc][r] + bias[gj];
            }
        }
}

// ---------------------------------------------------------------------------
// prep_qk: qkv fp32 -> q_hi/lo (x0.125), k_hi/lo in (bh, n, 64) bf16 layout.
// grid (BHT, NN/16), 256 threads: 16 rows x 16 lanes(x4 elems).
// ---------------------------------------------------------------------------
__global__ __launch_bounds__(256) void prep_qk(
    const float* __restrict__ qkv,
    u16* __restrict__ qh, u16* __restrict__ ql,
    u16* __restrict__ kh, u16* __restrict__ kl)
{
    const int bh = blockIdx.x;
    const int b = bh / NH, h = bh % NH;
    const int tid = threadIdx.x;
    const int r = tid >> 4, c = tid & 15;
    const int n = blockIdx.y * 16 + r;
    const size_t base = (size_t)(b * NN + n) * QKVC + h * HD + c * 4;
    const size_t obase = ((size_t)bh * NN + n) * HD + c * 4;

    float4 qv = *(const float4*)&qkv[base];
    u16x4 hh, ll;
    bfp s;
    s = splitf(qv.x * 0.125f); hh[0] = s.h; ll[0] = s.l;
    s = splitf(qv.y * 0.125f); hh[1] = s.h; ll[1] = s.l;
    s = splitf(qv.z * 0.125f); hh[2] = s.h; ll[2] = s.l;
    s = splitf(qv.w * 0.125f); hh[3] = s.h; ll[3] = s.l;
    *(u16x4*)&qh[obase] = hh; *(u16x4*)&ql[obase] = ll;

    float4 kv = *(const float4*)&qkv[base + DIMC];
    s = splitf(kv.x); hh[0] = s.h; ll[0] = s.l;
    s = splitf(kv.y); hh[1] = s.h; ll[1] = s.l;
    s = splitf(kv.z); hh[2] = s.h; ll[2] = s.l;
    s = splitf(kv.w); hh[3] = s.h; ll[3] = s.l;
    *(u16x4*)&kh[obase] = hh; *(u16x4*)&kl[obase] = ll;
}

// ---------------------------------------------------------------------------
// prep_vt: v (inside qkv) -> v^T hi/lo, (bh, d=64, n=1024) bf16.
// grid (16 n-tiles, BHT). LDS 64x64 fp32 transpose.
// ---------------------------------------------------------------------------
__global__ __launch_bounds__(256) void prep_vt(
    const float* __restrict__ qkv, u16* __restrict__ vth, u16* __restrict__ vtl)
{
    __shared__ float t[64][65];
    const int n0 = blockIdx.x * 64;
    const int bh = blockIdx.y;
    const int b = bh / NH, h = bh % NH;
    const int tid = threadIdx.x;

    const int r = tid >> 2, ch = tid & 3;
    const size_t src = (size_t)(b * NN + n0 + r) * QKVC + 2 * DIMC + h * HD + ch * 16;
#pragma unroll
    for (int e = 0; e < 16; e += 4) {
        float4 v = *(const float4*)&qkv[src + e];
        t[r][ch * 16 + e + 0] = v.x; t[r][ch * 16 + e + 1] = v.y;
        t[r][ch * 16 + e + 2] = v.z; t[r][ch * 16 + e + 3] = v.w;
    }
    __syncthreads();

    const int d = tid >> 2, oc = tid & 3;
    u16x8 h0, l0, h1, l1;
    bfp s;
#pragma unroll
    for (int e = 0; e < 8; ++e) {
        s = splitf(t[oc * 16 + e][d]); h0[e] = s.h; l0[e] = s.l;
    }
#pragma unroll
    for (int e = 0; e < 8; ++e) {
        s = splitf(t[oc * 16 + 8 + e][d]); h1[e] = s.h; l1[e] = s.l;
    }
    const size_t dst = ((size_t)bh * HD + d) * NN + n0 + oc * 16;
    *(u16x8*)&vth[dst] = h0; *(u16x8*)&vth[dst + 8] = h1;
    *(u16x8*)&vtl[dst] = l0; *(u16x8*)&vtl[dst + 8] = l1;
}

// ---------------------------------------------------------------------------
// qk_mfma: S = (q*0.125) @ k^T per head, split 3-term. K=64.
// grid (8, 8, CH). Output S fp32.
// ---------------------------------------------------------------------------
__global__ __launch_bounds__(256) void qk_mfma(
    const u16* __restrict__ qh, const u16* __restrict__ ql,
    const u16* __restrict__ kh, const u16* __restrict__ kl,
    float* __restrict__ Sb, int h0)
{
    __shared__ u16 sAh[128 * 32], sAl[128 * 32], sBh[128 * 32], sBl[128 * 32];
    const int tid = threadIdx.x;
    const int j0 = blockIdx.x * 128, i0 = blockIdx.y * 128;
    const int bhl = blockIdx.z;
    const int bh = h0 + bhl;
    const int srow = tid >> 1, shalf = (tid & 1) * 16;
    const int w = tid >> 6, l = tid & 63;
    const int wr = w >> 1, wc = w & 1;
    const int l15 = l & 15, kb4 = l >> 4;

    f32x4 acc[4][4];
    const f32x4 zero = {0.f, 0.f, 0.f, 0.f};
#pragma unroll
    for (int a = 0; a < 4; ++a)
#pragma unroll
        for (int b = 0; b < 4; ++b) acc[a][b] = zero;

    for (int k0 = 0; k0 < HD; k0 += 32) {
        const size_t ar = ((size_t)bh * NN + i0 + srow) * HD + k0 + shalf;
        const size_t br = ((size_t)bh * NN + j0 + srow) * HD + k0 + shalf;
        const int so = srow * 32 + shalf;
        *(u16x8*)&sAh[so]     = *(const u16x8*)&qh[ar];
        *(u16x8*)&sAh[so + 8] = *(const u16x8*)&qh[ar + 8];
        *(u16x8*)&sAl[so]     = *(const u16x8*)&ql[ar];
        *(u16x8*)&sAl[so + 8] = *(const u16x8*)&ql[ar + 8];
        *(u16x8*)&sBh[so]     = *(const u16x8*)&kh[br];
        *(u16x8*)&sBh[so + 8] = *(const u16x8*)&kh[br + 8];
        *(u16x8*)&sBl[so]     = *(const u16x8*)&kl[br];
        *(u16x8*)&sBl[so + 8] = *(const u16x8*)&kl[br + 8];
        __syncthreads();

        s16x8 ah[4], al[4], bh[4], bl[4];
#pragma unroll
        for (int f = 0; f < 4; ++f) {
            const int ao = (wr * 64 + f * 16 + l15) * 32 + kb4 * 8;
            const int bo = (wc * 64 + f * 16 + l15) * 32 + kb4 * 8;
            ah[f] = *(const s16x8*)&sAh[ao];
            al[f] = *(const s16x8*)&sAl[ao];
            bh[f] = *(const s16x8*)&sBh[bo];
            bl[f] = *(const s16x8*)&sBl[bo];
        }
#pragma unroll
        for (int fr = 0; fr < 4; ++fr)
#pragma unroll
            for (int fc = 0; fc < 4; ++fc) {
                acc[fr][fc] = __builtin_amdgcn_mfma_f32_16x16x32_bf16(
                    ah[fr], bh[fc], acc[fr][fc], 0, 0, 0);
                acc[fr][fc] = __builtin_amdgcn_mfma_f32_16x16x32_bf16(
                    ah[fr], bl[fc], acc[fr][fc], 0, 0, 0);
                acc[fr][fc] = __builtin_amdgcn_mfma_f32_16x16x32_bf16(
                    al[fr], bh[fc], acc[fr][fc], 0, 0, 0);
            }
        __syncthreads();
    }

    float* Sh = Sb + (size_t)bhl * NN * NN;
#pragma unroll
    for (int fr = 0; fr < 4; ++fr)
#pragma unroll
        for (int r = 0; r < 4; ++r) {
            const int gi = i0 + wr * 64 + fr * 16 + kb4 * 4 + r;
#pragma unroll
            for (int fc = 0; fc < 4; ++fc) {
                const int gj = j0 + wc * 64 + fc * 16 + l15;
                Sh[(size_t)gi * NN + gj] = acc[fr][fc][r];
            }
        }
}

// ---------------------------------------------------------------------------
// softmax: read S fp32 row, write A bf16 row. grid CH*NN blocks of 256.
// ---------------------------------------------------------------------------
__global__ __launch_bounds__(256) void softmax_b(
    const float* __restrict__ Sb, u16* __restrict__ Abf)
{
    const int row = blockIdx.x;
    const float* p = Sb + (size_t)row * NN;
    u16* q = Abf + (size_t)row * NN;
    const int tid = threadIdx.x;
    __shared__ float redm[4], reds[4];

    float4 v = *(const float4*)&p[tid * 4];
    float m = fmaxf(fmaxf(v.x, v.y), fmaxf(v.z, v.w));
#pragma unroll
    for (int off = 32; off >= 1; off >>= 1) m = fmaxf(m, __shfl_xor(m, off));
    if ((tid & 63) == 0) redm[tid >> 6] = m;
    __syncthreads();
    m = fmaxf(fmaxf(redm[0], redm[1]), fmaxf(redm[2], redm[3]));

    v.x = expf(v.x - m); v.y = expf(v.y - m);
    v.z = expf(v.z - m); v.w = expf(v.w - m);
    float s = v.x + v.y + v.z + v.w;
#pragma unroll
    for (int off = 32; off >= 1; off >>= 1) s += __shfl_xor(s, off);
    if ((tid & 63) == 0) reds[tid >> 6] = s;
    __syncthreads();
    s = reds[0] + reds[1] + reds[2] + reds[3];

    const float inv = 1.0f / s;
    u16x4 o;
    o[0] = f2bf(v.x * inv); o[1] = f2bf(v.y * inv);
    o[2] = f2bf(v.z * inv); o[3] = f2bf(v.w * inv);
    *(u16x4*)&q[tid * 4] = o;
}

// ---------------------------------------------------------------------------
// transpose bf16 -> bf16 per head. 64x64 tiles, grid (16,16,CH).
// ---------------------------------------------------------------------------
__global__ __launch_bounds__(256) void transpose_b2b(
    const u16* __restrict__ src0, u16* __restrict__ dst0)
{
    __shared__ u16 t[64][65];
    const int tid = threadIdx.x;
    const int j0 = blockIdx.x * 64, i0 = blockIdx.y * 64;
    const int bz = blockIdx.z;
    const u16* src = src0 + (size_t)bz * NN * NN;
    u16* dst = dst0 + (size_t)bz * NN * NN;

    const int row = tid >> 2, ch = tid & 3;
    const size_t sp = (size_t)(i0 + row) * NN + j0 + ch * 16;
    u16x8 v0 = *(const u16x8*)&src[sp];
    u16x8 v1 = *(const u16x8*)&src[sp + 8];
#pragma unroll
    for (int e = 0; e < 8; ++e) { t[row][ch * 16 + e] = v0[e]; t[row][ch * 16 + 8 + e] = v1[e]; }
    __syncthreads();

    const int oj = tid >> 2, och = tid & 3;
    u16x8 o0, o1;
#pragma unroll
    for (int e = 0; e < 8; ++e) o0[e] = t[och * 16 + e][oj];
#pragma unroll
    for (int e = 0; e < 8; ++e) o1[e] = t[och * 16 + 8 + e][oj];
    const size_t dp = (size_t)(j0 + oj) * NN + i0 + och * 16;
    *(u16x8*)&dst[dp] = o0;
    *(u16x8*)&dst[dp + 8] = o1;
}

// ---------------------------------------------------------------------------
// mpow: P = A@A (bf16 MFMA); M = relu(del*I + c1*A + c2*P) -> bf16 + rowsum.
// grid (8, 8, CH), 128x128 tile, BK=32.
// ---------------------------------------------------------------------------
__global__ __launch_bounds__(256) void mpow_mfma(
    const u16* __restrict__ Abf, const u16* __restrict__ Atb,
    u16* __restrict__ Mb, float* __restrict__ rowsum,
    const float* __restrict__ lamb, const float* __restrict__ gamma,
    const float* __restrict__ delta, int h0)
{
    __shared__ u16 sA[128 * 32], sB[128 * 32];
    const int tid = threadIdx.x;
    const int j0 = blockIdx.x * 128, i0 = blockIdx.y * 128;
    const int bz = blockIdx.z;
    const int h = (h0 + bz) % NH;
    const u16* Ah = Abf + (size_t)bz * NN * NN;
    const u16* Ath = Atb + (size_t)bz * NN * NN;

    const int srow = tid >> 1, shalf = (tid & 1) * 16;
    const int w = tid >> 6, l = tid & 63;
    const int wr = w >> 1, wc = w & 1;
    const int l15 = l & 15, kb4 = l >> 4;

    f32x4 acc[4][4];
    const f32x4 zero = {0.f, 0.f, 0.f, 0.f};
#pragma unroll
    for (int a = 0; a < 4; ++a)
#pragma unroll
        for (int b = 0; b < 4; ++b) acc[a][b] = zero;

    for (int k0 = 0; k0 < NN; k0 += 32) {
        const size_t ar = (size_t)(i0 + srow) * NN + k0 + shalf;
        const size_t br = (size_t)(j0 + srow) * NN + k0 + shalf;
        const int so = srow * 32 + shalf;
        *(u16x8*)&sA[so]     = *(const u16x8*)&Ah[ar];
        *(u16x8*)&sA[so + 8] = *(const u16x8*)&Ah[ar + 8];
        *(u16x8*)&sB[so]     = *(const u16x8*)&Ath[br];
        *(u16x8*)&sB[so + 8] = *(const u16x8*)&Ath[br + 8];
        __syncthreads();

        s16x8 af[4], bf[4];
#pragma unroll
        for (int f = 0; f < 4; ++f) {
            af[f] = *(const s16x8*)&sA[(wr * 64 + f * 16 + l15) * 32 + kb4 * 8];
            bf[f] = *(const s16x8*)&sB[(wc * 64 + f * 16 + l15) * 32 + kb4 * 8];
        }
#pragma unroll
        for (int fr = 0; fr < 4; ++fr)
#pragma unroll
            for (int fc = 0; fc < 4; ++fc)
                acc[fr][fc] = __builtin_amdgcn_mfma_f32_16x16x32_bf16(
                    af[fr], bf[fc], acc[fr][fc], 0, 0, 0);
        __syncthreads();
    }

    const float lam = lamb[h];
    const float c1 = gamma[h] - 6.0f * lam;
    const float c2 = 7.0f * lam;
    const float del = delta[h];
    u16* Mh = Mb + (size_t)bz * NN * NN;
    float* rsh = rowsum + bz * NN;

#pragma unroll
    for (int fr = 0; fr < 4; ++fr)
#pragma unroll
        for (int r = 0; r < 4; ++r) {
            const int gi = i0 + wr * 64 + fr * 16 + kb4 * 4 + r;
            float rowacc = 0.f;
#pragma unroll
            for (int fc = 0; fc < 4; ++fc) {
                const int gj = j0 + wc * 64 + fc * 16 + l15;
                const float a = bf2f(Ah[(size_t)gi * NN + gj]);
                float m = c2 * acc[fr][fc][r] + c1 * a + (gi == gj ? del : 0.f);
                m = fmaxf(m, 0.f);
                const u16 mb16 = f2bf(m);
                Mh[(size_t)gi * NN + gj] = mb16;
                rowacc += bf2f(mb16);
            }
            rowacc += __shfl_xor(rowacc, 1);
            rowacc += __shfl_xor(rowacc, 2);
            rowacc += __shfl_xor(rowacc, 4);
            rowacc += __shfl_xor(rowacc, 8);
            if (l15 == 0) atomicAdd(&rsh[gi], rowacc);
        }
}

// ---------------------------------------------------------------------------
// pv: ao = (M / rowsum) @ V via MFMA, V as v^T hi/lo (2-term split).
// grid (8 i-tiles, CH). Tile 128 x 64, 4 waves stacked in i. Writes ao hi/lo.
// ---------------------------------------------------------------------------
__global__ __launch_bounds__(256) void pv_mfma(
    const u16* __restrict__ Mb, const float* __restrict__ rowsum,
    const u16* __restrict__ vth, const u16* __restrict__ vtl,
    u16* __restrict__ aoh, u16* __restrict__ aol, int h0)
{
    __shared__ u16 sM[128 * 32], sVh[64 * 32], sVl[64 * 32];
    const int tid = threadIdx.x;
    const int i0 = blockIdx.x * 128;
    const int bhl = blockIdx.y;
    const int bh = h0 + bhl;
    const int b = bh / NH, h = bh % NH;
    const u16* Mh = Mb + (size_t)bhl * NN * NN;
    const u16* vhb = vth + (size_t)bh * HD * NN;
    const u16* vlb = vtl + (size_t)bh * HD * NN;

    const int srow = tid >> 1, shalf = (tid & 1) * 16;
    const int vrow = tid >> 2, vq = (tid & 3) * 8;
    const int w = tid >> 6, l = tid & 63;
    const int l15 = l & 15, kb4 = l >> 4;

    f32x4 acc[2][4];
    const f32x4 zero = {0.f, 0.f, 0.f, 0.f};
#pragma unroll
    for (int a = 0; a < 2; ++a)
#pragma unroll
        for (int c = 0; c < 4; ++c) acc[a][c] = zero;

    for (int k0 = 0; k0 < NN; k0 += 32) {
        const size_t mr = (size_t)(i0 + srow) * NN + k0 + shalf;
        const int so = srow * 32 + shalf;
        *(u16x8*)&sM[so]     = *(const u16x8*)&Mh[mr];
        *(u16x8*)&sM[so + 8] = *(const u16x8*)&Mh[mr + 8];
        const size_t vr = (size_t)vrow * NN + k0 + vq;
        *(u16x8*)&sVh[vrow * 32 + vq] = *(const u16x8*)&vhb[vr];
        *(u16x8*)&sVl[vrow * 32 + vq] = *(const u16x8*)&vlb[vr];
        __syncthreads();

        s16x8 af[2], bh[4], bl[4];
#pragma unroll
        for (int f = 0; f < 2; ++f)
            af[f] = *(const s16x8*)&sM[(w * 32 + f * 16 + l15) * 32 + kb4 * 8];
#pragma unroll
        for (int f = 0; f < 4; ++f) {
            bh[f] = *(const s16x8*)&sVh[(f * 16 + l15) * 32 + kb4 * 8];
            bl[f] = *(const s16x8*)&sVl[(f * 16 + l15) * 32 + kb4 * 8];
        }
#pragma unroll
        for (int fr = 0; fr < 2; ++fr)
#pragma unroll
            for (int fc = 0; fc < 4; ++fc) {
                acc[fr][fc] = __builtin_amdgcn_mfma_f32_16x16x32_bf16(
                    af[fr], bh[fc], acc[fr][fc], 0, 0, 0);
                acc[fr][fc] = __builtin_amdgcn_mfma_f32_16x16x32_bf16(
                    af[fr], bl[fc], acc[fr][fc], 0, 0, 0);
            }
        __syncthreads();
    }

#pragma unroll
    for (int fr = 0; fr < 2; ++fr)
#pragma unroll
        for (int r = 0; r < 4; ++r) {
            const int gi = i0 + w * 32 + fr * 16 + kb4 * 4 + r;
            const float inv = 1.0f / (rowsum[bhl * NN + gi] + 1e-9f);
            const size_t ob = (size_t)(b * NN + gi) * DIMC + h * HD;
#pragma unroll
            for (int fc = 0; fc < 4; ++fc) {
                const int gd = fc * 16 + l15;
                bfp s = splitf(acc[fr][fc][r] * inv);
                aoh[ob + gd] = s.h;
                aol[ob + gd] = s.l;
            }
        }
}

// ---------------------------------------------------------------------------
extern "C" void kernel_launch(void* const* d_in, const int* in_sizes, int n_in,
                              void* d_out, int out_size, void* d_ws, size_t ws_size,
                              hipStream_t stream)
{
    const float* x      = (const float*)d_in[0];
    const float* qkv_w  = (const float*)d_in[1];
    const float* qkv_b  = (const float*)d_in[2];
    const float* proj_w = (const float*)d_in[3];
    const float* proj_b = (const float*)d_in[4];
    const float* lamb   = (const float*)d_in[5];
    const float* gamma  = (const float*)d_in[6];
    const float* delta  = (const float*)d_in[7];

    char* p = (char*)d_ws;
    float* qkvb = (float*)p;                p += (size_t)4096 * QKVC * 4;
    u16* xh  = (u16*)p;                     p += (size_t)4096 * DIMC * 2;
    u16* xl  = (u16*)p;                     p += (size_t)4096 * DIMC * 2;
    u16* wh  = (u16*)p;                     p += (size_t)QKVC * DIMC * 2;
    u16* wl  = (u16*)p;                     p += (size_t)QKVC * DIMC * 2;
    u16* pwh = (u16*)p;                     p += (size_t)DIMC * DIMC * 2;
    u16* pwl = (u16*)p;                     p += (size_t)DIMC * DIMC * 2;
    u16* qh  = (u16*)p;                     p += (size_t)BHT * NN * HD * 2;
    u16* ql  = (u16*)p;                     p += (size_t)BHT * NN * HD * 2;
    u16* kh  = (u16*)p;                     p += (size_t)BHT * NN * HD * 2;
    u16* kl  = (u16*)p;                     p += (size_t)BHT * NN * HD * 2;
    u16* vth = (u16*)p;                     p += (size_t)BHT * HD * NN * 2;
    u16* vtl = (u16*)p;                     p += (size_t)BHT * HD * NN * 2;
    u16* aoh = (u16*)p;                     p += (size_t)4096 * DIMC * 2;
    u16* aol = (u16*)p;                     p += (size_t)4096 * DIMC * 2;
    const size_t fixed = (size_t)(p - (char*)d_ws);

    // per-head: S fp32 4MB (M bf16 aliases into it) + A 2MB + At 2MB + rs 4KB
    const size_t perh = (size_t)NN * NN * 4 + 2 * (size_t)NN * NN * 2 + NN * 4;
    static const int choices[] = {48, 24, 16, 12, 8, 6, 4, 3, 2, 1};
    int CH = 1;
    for (int ci = 0; ci < 10; ++ci) {
        int c = choices[ci];
        if (fixed + (size_t)c * perh <= ws_size) { CH = c; break; }
    }

    float* Sb = (float*)p;                  p += (size_t)CH * NN * NN * 4;
    u16* Abf  = (u16*)p;                    p += (size_t)CH * NN * NN * 2;
    u16* Atb  = (u16*)p;                    p += (size_t)CH * NN * NN * 2;
    float* rs = (float*)p;
    u16* Mb   = (u16*)Sb;                   // alias: S dead after softmax

    // 0) splits of inputs
    split_f2b<<<dim3((4096 * DIMC / 4 + 255) / 256), 256, 0, stream>>>(x, xh, xl, 4096 * DIMC / 4);
    split_f2b<<<dim3((QKVC * DIMC / 4 + 255) / 256), 256, 0, stream>>>(qkv_w, wh, wl, QKVC * DIMC / 4);
    split_f2b<<<dim3((DIMC * DIMC / 4 + 255) / 256), 256, 0, stream>>>(proj_w, pwh, pwl, DIMC * DIMC / 4);

    // 1) qkv = x @ qkv_w^T + qkv_b
    gemm3_mfma<<<dim3(QKVC / 128, 4096 / 128), 256, 0, stream>>>(
        4096, QKVC, DIMC, xh, xl, wh, wl, qkv_b, qkvb);

    // 1b) per-head splits of q,k (scale folded) and v^T
    prep_qk<<<dim3(BHT, NN / 16), 256, 0, stream>>>(qkvb, qh, ql, kh, kl);
    prep_vt<<<dim3(NN / 64, BHT), 256, 0, stream>>>(qkvb, vth, vtl);

    // 2..5) per chunk of heads
    for (int h0 = 0; h0 < BHT; h0 += CH) {
        qk_mfma<<<dim3(8, 8, CH), 256, 0, stream>>>(qh, ql, kh, kl, Sb, h0);
        softmax_b<<<dim3(CH * NN), 256, 0, stream>>>(Sb, Abf);
        transpose_b2b<<<dim3(16, 16, CH), 256, 0, stream>>>(Abf, Atb);
        hipMemsetAsync(rs, 0, (size_t)CH * NN * sizeof(float), stream);
        mpow_mfma<<<dim3(8, 8, CH), 256, 0, stream>>>(
            Abf, Atb, Mb, rs, lamb, gamma, delta, h0);
        pv_mfma<<<dim3(8, CH), 256, 0, stream>>>(Mb, rs, vth, vtl, aoh, aol, h0);
    }

    // 6) final = ao @ proj_w^T + proj_b
    gemm3_mfma<<<dim3(DIMC / 128, 4096 / 128), 256, 0, stream>>>(
        4096, DIMC, DIMC, aoh, aol, pwh, pwl, proj_b, (float*)d_out);
}

// Round 6
// 547.837 us; speedup vs baseline: 3.4888x; 1.1152x over previous
//
#include <hip/hip_runtime.h>
#include <hip/hip_bf16.h>

#define DIMC 768
#define NH 12
#define HD 64
#define BB 4
#define NN 1024
#define BHT 48          // BB*NH
#define QKVC 2304       // 3*DIM

typedef unsigned short u16;
typedef __attribute__((ext_vector_type(4))) unsigned short u16x4;
typedef __attribute__((ext_vector_type(8))) unsigned short u16x8;
typedef __attribute__((ext_vector_type(8))) short s16x8;
typedef __attribute__((ext_vector_type(4))) float f32x4;

// async global->LDS, 16B per lane; lds base must be wave-uniform.
#define GLD16(g, l) __builtin_amdgcn_global_load_lds( \
    (__attribute__((address_space(1))) void*)(g),     \
    (__attribute__((address_space(3))) void*)(l), 16, 0, 0)

__device__ __forceinline__ u16 f2bf(float f) {
    unsigned u = __float_as_uint(f);
    return (u16)((u + 0x7FFF + ((u >> 16) & 1)) >> 16);   // RNE
}
__device__ __forceinline__ float bf2f(u16 v) {
    return __uint_as_float(((unsigned)v) << 16);
}
struct bfp { u16 h, l; };
__device__ __forceinline__ bfp splitf(float f) {
    bfp r;
    r.h = f2bf(f);
    r.l = f2bf(f - bf2f(r.h));      // exact residual, bf16-rounded
    return r;
}

// ---------------------------------------------------------------------------
// Elementwise split: src fp32 -> (hi, lo) bf16. n multiple of 4.
// ---------------------------------------------------------------------------
__global__ __launch_bounds__(256) void split_f2b(
    const float* __restrict__ src, u16* __restrict__ hi, u16* __restrict__ lo,
    int n4)
{
    int idx = blockIdx.x * 256 + threadIdx.x;
    if (idx >= n4) return;
    float4 v = *(const float4*)&src[idx * 4];
    u16x4 h, l;
    bfp s;
    s = splitf(v.x); h[0] = s.h; l[0] = s.l;
    s = splitf(v.y); h[1] = s.h; l[1] = s.l;
    s = splitf(v.z); h[2] = s.h; l[2] = s.l;
    s = splitf(v.w); h[3] = s.h; l[3] = s.l;
    *(u16x4*)&hi[idx * 4] = h;
    *(u16x4*)&lo[idx * 4] = l;
}

// ---------------------------------------------------------------------------
// Generic split-bf16 GEMM: C = A @ B^T + bias (3-term MFMA, ~fp32 accuracy).
// A:(M,K) B:(N,K) row-major via hi/lo bf16 pairs. 128x128 tile, BK=32.
// grid (N/128, M/128), 256 threads (4 waves, 2x2). global_load_lds staging.
// ---------------------------------------------------------------------------
__global__ __launch_bounds__(256) void gemm3_mfma(
    int Mrows, int Nout, int K,
    const u16* __restrict__ Ahp, const u16* __restrict__ Alp,
    const u16* __restrict__ Bhp, const u16* __restrict__ Blp,
    const float* __restrict__ bias, float* __restrict__ C)
{
    __shared__ alignas(16) u16 sAh[128 * 32], sAl[128 * 32], sBh[128 * 32], sBl[128 * 32];
    const int tid = threadIdx.x;
    const int j0 = blockIdx.x * 128, i0 = blockIdx.y * 128;
    const int w = tid >> 6, l = tid & 63;
    const int wr = w >> 1, wc = w & 1;
    const int l15 = l & 15, kb4 = l >> 4;
    const int lrow = l >> 2, lch = (l & 3) * 8;

    f32x4 acc[4][4];
    const f32x4 zero = {0.f, 0.f, 0.f, 0.f};
#pragma unroll
    for (int a = 0; a < 4; ++a)
#pragma unroll
        for (int b = 0; b < 4; ++b) acc[a][b] = zero;

    for (int k0 = 0; k0 < K; k0 += 32) {
#pragma unroll
        for (int t = 0; t < 2; ++t) {
            const int r = w * 32 + t * 16;          // 16-row group base
            const size_t ar = (size_t)(i0 + r + lrow) * K + k0 + lch;
            const size_t br = (size_t)(j0 + r + lrow) * K + k0 + lch;
            GLD16(&Ahp[ar], &sAh[r * 32]);
            GLD16(&Alp[ar], &sAl[r * 32]);
            GLD16(&Bhp[br], &sBh[r * 32]);
            GLD16(&Blp[br], &sBl[r * 32]);
        }
        __syncthreads();

        s16x8 ah[4], al[4], bh[4], bl[4];
#pragma unroll
        for (int f = 0; f < 4; ++f) {
            const int ao = (wr * 64 + f * 16 + l15) * 32 + kb4 * 8;
            const int bo = (wc * 64 + f * 16 + l15) * 32 + kb4 * 8;
            ah[f] = *(const s16x8*)&sAh[ao];
            al[f] = *(const s16x8*)&sAl[ao];
            bh[f] = *(const s16x8*)&sBh[bo];
            bl[f] = *(const s16x8*)&sBl[bo];
        }
#pragma unroll
        for (int fr = 0; fr < 4; ++fr)
#pragma unroll
            for (int fc = 0; fc < 4; ++fc) {
                acc[fr][fc] = __builtin_amdgcn_mfma_f32_16x16x32_bf16(
                    ah[fr], bh[fc], acc[fr][fc], 0, 0, 0);
                acc[fr][fc] = __builtin_amdgcn_mfma_f32_16x16x32_bf16(
                    ah[fr], bl[fc], acc[fr][fc], 0, 0, 0);
                acc[fr][fc] = __builtin_amdgcn_mfma_f32_16x16x32_bf16(
                    al[fr], bh[fc], acc[fr][fc], 0, 0, 0);
            }
        __syncthreads();
    }

#pragma unroll
    for (int fr = 0; fr < 4; ++fr)
#pragma unroll
        for (int r = 0; r < 4; ++r) {
            const int gi = i0 + wr * 64 + fr * 16 + kb4 * 4 + r;
#pragma unroll
            for (int fc = 0; fc < 4; ++fc) {
                const int gj = j0 + wc * 64 + fc * 16 + l15;
                C[(size_t)gi * Nout + gj] = acc[fr][fc][r] + bias[gj];
            }
        }
}

// ---------------------------------------------------------------------------
// prep_qk: qkv fp32 -> q_hi/lo (x0.125), k_hi/lo in (bh, n, 64) bf16 layout.
// ---------------------------------------------------------------------------
__global__ __launch_bounds__(256) void prep_qk(
    const float* __restrict__ qkv,
    u16* __restrict__ qh, u16* __restrict__ ql,
    u16* __restrict__ kh, u16* __restrict__ kl)
{
    const int bh = blockIdx.x;
    const int b = bh / NH, h = bh % NH;
    const int tid = threadIdx.x;
    const int r = tid >> 4, c = tid & 15;
    const int n = blockIdx.y * 16 + r;
    const size_t base = (size_t)(b * NN + n) * QKVC + h * HD + c * 4;
    const size_t obase = ((size_t)bh * NN + n) * HD + c * 4;

    float4 qv = *(const float4*)&qkv[base];
    u16x4 hh, ll;
    bfp s;
    s = splitf(qv.x * 0.125f); hh[0] = s.h; ll[0] = s.l;
    s = splitf(qv.y * 0.125f); hh[1] = s.h; ll[1] = s.l;
    s = splitf(qv.z * 0.125f); hh[2] = s.h; ll[2] = s.l;
    s = splitf(qv.w * 0.125f); hh[3] = s.h; ll[3] = s.l;
    *(u16x4*)&qh[obase] = hh; *(u16x4*)&ql[obase] = ll;

    float4 kv = *(const float4*)&qkv[base + DIMC];
    s = splitf(kv.x); hh[0] = s.h; ll[0] = s.l;
    s = splitf(kv.y); hh[1] = s.h; ll[1] = s.l;
    s = splitf(kv.z); hh[2] = s.h; ll[2] = s.l;
    s = splitf(kv.w); hh[3] = s.h; ll[3] = s.l;
    *(u16x4*)&kh[obase] = hh; *(u16x4*)&kl[obase] = ll;
}

// ---------------------------------------------------------------------------
// prep_vt: v (inside qkv) -> v^T hi/lo, (bh, d=64, n=1024) bf16.
// ---------------------------------------------------------------------------
__global__ __launch_bounds__(256) void prep_vt(
    const float* __restrict__ qkv, u16* __restrict__ vth, u16* __restrict__ vtl)
{
    __shared__ float t[64][65];
    const int n0 = blockIdx.x * 64;
    const int bh = blockIdx.y;
    const int b = bh / NH, h = bh % NH;
    const int tid = threadIdx.x;

    const int r = tid >> 2, ch = tid & 3;
    const size_t src = (size_t)(b * NN + n0 + r) * QKVC + 2 * DIMC + h * HD + ch * 16;
#pragma unroll
    for (int e = 0; e < 16; e += 4) {
        float4 v = *(const float4*)&qkv[src + e];
        t[r][ch * 16 + e + 0] = v.x; t[r][ch * 16 + e + 1] = v.y;
        t[r][ch * 16 + e + 2] = v.z; t[r][ch * 16 + e + 3] = v.w;
    }
    __syncthreads();

    const int d = tid >> 2, oc = tid & 3;
    u16x8 h0, l0, h1, l1;
    bfp s;
#pragma unroll
    for (int e = 0; e < 8; ++e) {
        s = splitf(t[oc * 16 + e][d]); h0[e] = s.h; l0[e] = s.l;
    }
#pragma unroll
    for (int e = 0; e < 8; ++e) {
        s = splitf(t[oc * 16 + 8 + e][d]); h1[e] = s.h; l1[e] = s.l;
    }
    const size_t dst = ((size_t)bh * HD + d) * NN + n0 + oc * 16;
    *(u16x8*)&vth[dst] = h0; *(u16x8*)&vth[dst + 8] = h1;
    *(u16x8*)&vtl[dst] = l0; *(u16x8*)&vtl[dst + 8] = l1;
}

// ---------------------------------------------------------------------------
// qk_mfma: S = (q*0.125) @ k^T per head, split 3-term. K=64.
// grid (8, 8, CH). Output S fp32. global_load_lds staging.
// ---------------------------------------------------------------------------
__global__ __launch_bounds__(256) void qk_mfma(
    const u16* __restrict__ qh, const u16* __restrict__ ql,
    const u16* __restrict__ kh, const u16* __restrict__ kl,
    float* __restrict__ Sb, int h0)
{
    __shared__ alignas(16) u16 sAh[128 * 32], sAl[128 * 32], sBh[128 * 32], sBl[128 * 32];
    const int tid = threadIdx.x;
    const int j0 = blockIdx.x * 128, i0 = blockIdx.y * 128;
    const int bhl = blockIdx.z;
    const int bh = h0 + bhl;
    const int w = tid >> 6, l = tid & 63;
    const int wr = w >> 1, wc = w & 1;
    const int l15 = l & 15, kb4 = l >> 4;
    const int lrow = l >> 2, lch = (l & 3) * 8;

    f32x4 acc[4][4];
    const f32x4 zero = {0.f, 0.f, 0.f, 0.f};
#pragma unroll
    for (int a = 0; a < 4; ++a)
#pragma unroll
        for (int b = 0; b < 4; ++b) acc[a][b] = zero;

    for (int k0 = 0; k0 < HD; k0 += 32) {
#pragma unroll
        for (int t = 0; t < 2; ++t) {
            const int r = w * 32 + t * 16;
            const size_t ar = ((size_t)bh * NN + i0 + r + lrow) * HD + k0 + lch;
            const size_t br = ((size_t)bh * NN + j0 + r + lrow) * HD + k0 + lch;
            GLD16(&qh[ar], &sAh[r * 32]);
            GLD16(&ql[ar], &sAl[r * 32]);
            GLD16(&kh[br], &sBh[r * 32]);
            GLD16(&kl[br], &sBl[r * 32]);
        }
        __syncthreads();

        s16x8 ah[4], al[4], bh[4], bl[4];
#pragma unroll
        for (int f = 0; f < 4; ++f) {
            const int ao = (wr * 64 + f * 16 + l15) * 32 + kb4 * 8;
            const int bo = (wc * 64 + f * 16 + l15) * 32 + kb4 * 8;
            ah[f] = *(const s16x8*)&sAh[ao];
            al[f] = *(const s16x8*)&sAl[ao];
            bh[f] = *(const s16x8*)&sBh[bo];
            bl[f] = *(const s16x8*)&sBl[bo];
        }
#pragma unroll
        for (int fr = 0; fr < 4; ++fr)
#pragma unroll
            for (int fc = 0; fc < 4; ++fc) {
                acc[fr][fc] = __builtin_amdgcn_mfma_f32_16x16x32_bf16(
                    ah[fr], bh[fc], acc[fr][fc], 0, 0, 0);
                acc[fr][fc] = __builtin_amdgcn_mfma_f32_16x16x32_bf16(
                    ah[fr], bl[fc], acc[fr][fc], 0, 0, 0);
                acc[fr][fc] = __builtin_amdgcn_mfma_f32_16x16x32_bf16(
                    al[fr], bh[fc], acc[fr][fc], 0, 0, 0);
            }
        __syncthreads();
    }

    float* Sh = Sb + (size_t)bhl * NN * NN;
#pragma unroll
    for (int fr = 0; fr < 4; ++fr)
#pragma unroll
        for (int r = 0; r < 4; ++r) {
            const int gi = i0 + wr * 64 + fr * 16 + kb4 * 4 + r;
#pragma unroll
            for (int fc = 0; fc < 4; ++fc) {
                const int gj = j0 + wc * 64 + fc * 16 + l15;
                Sh[(size_t)gi * NN + gj] = acc[fr][fc][r];
            }
        }
}

// ---------------------------------------------------------------------------
// softmax: read S fp32 row, write A bf16 row. grid CH*NN blocks of 256.
// ---------------------------------------------------------------------------
__global__ __launch_bounds__(256) void softmax_b(
    const float* __restrict__ Sb, u16* __restrict__ Abf)
{
    const int row = blockIdx.x;
    const float* p = Sb + (size_t)row * NN;
    u16* q = Abf + (size_t)row * NN;
    const int tid = threadIdx.x;
    __shared__ float redm[4], reds[4];

    float4 v = *(const float4*)&p[tid * 4];
    float m = fmaxf(fmaxf(v.x, v.y), fmaxf(v.z, v.w));
#pragma unroll
    for (int off = 32; off >= 1; off >>= 1) m = fmaxf(m, __shfl_xor(m, off));
    if ((tid & 63) == 0) redm[tid >> 6] = m;
    __syncthreads();
    m = fmaxf(fmaxf(redm[0], redm[1]), fmaxf(redm[2], redm[3]));

    v.x = expf(v.x - m); v.y = expf(v.y - m);
    v.z = expf(v.z - m); v.w = expf(v.w - m);
    float s = v.x + v.y + v.z + v.w;
#pragma unroll
    for (int off = 32; off >= 1; off >>= 1) s += __shfl_xor(s, off);
    if ((tid & 63) == 0) reds[tid >> 6] = s;
    __syncthreads();
    s = reds[0] + reds[1] + reds[2] + reds[3];

    const float inv = 1.0f / s;
    u16x4 o;
    o[0] = f2bf(v.x * inv); o[1] = f2bf(v.y * inv);
    o[2] = f2bf(v.z * inv); o[3] = f2bf(v.w * inv);
    *(u16x4*)&q[tid * 4] = o;
}

// ---------------------------------------------------------------------------
// transpose bf16 -> bf16 per head. 64x64 tiles, grid (16,16,CH).
// ---------------------------------------------------------------------------
__global__ __launch_bounds__(256) void transpose_b2b(
    const u16* __restrict__ src0, u16* __restrict__ dst0)
{
    __shared__ u16 t[64][65];
    const int tid = threadIdx.x;
    const int j0 = blockIdx.x * 64, i0 = blockIdx.y * 64;
    const int bz = blockIdx.z;
    const u16* src = src0 + (size_t)bz * NN * NN;
    u16* dst = dst0 + (size_t)bz * NN * NN;

    const int row = tid >> 2, ch = tid & 3;
    const size_t sp = (size_t)(i0 + row) * NN + j0 + ch * 16;
    u16x8 v0 = *(const u16x8*)&src[sp];
    u16x8 v1 = *(const u16x8*)&src[sp + 8];
#pragma unroll
    for (int e = 0; e < 8; ++e) { t[row][ch * 16 + e] = v0[e]; t[row][ch * 16 + 8 + e] = v1[e]; }
    __syncthreads();

    const int oj = tid >> 2, och = tid & 3;
    u16x8 o0, o1;
#pragma unroll
    for (int e = 0; e < 8; ++e) o0[e] = t[och * 16 + e][oj];
#pragma unroll
    for (int e = 0; e < 8; ++e) o1[e] = t[och * 16 + 8 + e][oj];
    const size_t dp = (size_t)(j0 + oj) * NN + i0 + och * 16;
    *(u16x8*)&dst[dp] = o0;
    *(u16x8*)&dst[dp + 8] = o1;
}

// ---------------------------------------------------------------------------
// mpow: P = A@A (bf16 MFMA); M = relu(del*I + c1*A + c2*P) -> bf16.
// grid (8, 8, CH), 128x128 tile, BK=32. global_load_lds staging. No rowsum
// (computed in pv via ones-MFMA).
// ---------------------------------------------------------------------------
__global__ __launch_bounds__(256) void mpow_mfma(
    const u16* __restrict__ Abf, const u16* __restrict__ Atb,
    u16* __restrict__ Mb,
    const float* __restrict__ lamb, const float* __restrict__ gamma,
    const float* __restrict__ delta, int h0)
{
    __shared__ alignas(16) u16 sA[128 * 32], sB[128 * 32];
    const int tid = threadIdx.x;
    const int j0 = blockIdx.x * 128, i0 = blockIdx.y * 128;
    const int bz = blockIdx.z;
    const int h = (h0 + bz) % NH;
    const u16* Ah = Abf + (size_t)bz * NN * NN;
    const u16* Ath = Atb + (size_t)bz * NN * NN;

    const int w = tid >> 6, l = tid & 63;
    const int wr = w >> 1, wc = w & 1;
    const int l15 = l & 15, kb4 = l >> 4;
    const int lrow = l >> 2, lch = (l & 3) * 8;

    f32x4 acc[4][4];
    const f32x4 zero = {0.f, 0.f, 0.f, 0.f};
#pragma unroll
    for (int a = 0; a < 4; ++a)
#pragma unroll
        for (int b = 0; b < 4; ++b) acc[a][b] = zero;

    for (int k0 = 0; k0 < NN; k0 += 32) {
#pragma unroll
        for (int t = 0; t < 2; ++t) {
            const int r = w * 32 + t * 16;
            GLD16(&Ah[(size_t)(i0 + r + lrow) * NN + k0 + lch], &sA[r * 32]);
            GLD16(&Ath[(size_t)(j0 + r + lrow) * NN + k0 + lch], &sB[r * 32]);
        }
        __syncthreads();

        s16x8 af[4], bf[4];
#pragma unroll
        for (int f = 0; f < 4; ++f) {
            af[f] = *(const s16x8*)&sA[(wr * 64 + f * 16 + l15) * 32 + kb4 * 8];
            bf[f] = *(const s16x8*)&sB[(wc * 64 + f * 16 + l15) * 32 + kb4 * 8];
        }
#pragma unroll
        for (int fr = 0; fr < 4; ++fr)
#pragma unroll
            for (int fc = 0; fc < 4; ++fc)
                acc[fr][fc] = __builtin_amdgcn_mfma_f32_16x16x32_bf16(
                    af[fr], bf[fc], acc[fr][fc], 0, 0, 0);
        __syncthreads();
    }

    const float lam = lamb[h];
    const float c1 = gamma[h] - 6.0f * lam;
    const float c2 = 7.0f * lam;
    const float del = delta[h];
    u16* Mh = Mb + (size_t)bz * NN * NN;

#pragma unroll
    for (int fr = 0; fr < 4; ++fr)
#pragma unroll
        for (int r = 0; r < 4; ++r) {
            const int gi = i0 + wr * 64 + fr * 16 + kb4 * 4 + r;
#pragma unroll
            for (int fc = 0; fc < 4; ++fc) {
                const int gj = j0 + wc * 64 + fc * 16 + l15;
                const float a = bf2f(Ah[(size_t)gi * NN + gj]);
                float m = c2 * acc[fr][fc][r] + c1 * a + (gi == gj ? del : 0.f);
                m = fmaxf(m, 0.f);
                Mh[(size_t)gi * NN + gj] = f2bf(m);
            }
        }
}

// ---------------------------------------------------------------------------
// pv: ao = (M @ V) / rowsum(M). V as v^T hi/lo (2-term split); rowsum via
// ones-fragment MFMA. grid (8 i-tiles, CH). Writes ao hi/lo.
// ---------------------------------------------------------------------------
__global__ __launch_bounds__(256) void pv_mfma(
    const u16* __restrict__ Mb,
    const u16* __restrict__ vth, const u16* __restrict__ vtl,
    u16* __restrict__ aoh, u16* __restrict__ aol, int h0)
{
    __shared__ alignas(16) u16 sM[128 * 32], sVh[64 * 32], sVl[64 * 32];
    const int tid = threadIdx.x;
    const int i0 = blockIdx.x * 128;
    const int bhl = blockIdx.y;
    const int bh = h0 + bhl;
    const int b = bh / NH, h = bh % NH;
    const u16* Mh = Mb + (size_t)bhl * NN * NN;
    const u16* vhb = vth + (size_t)bh * HD * NN;
    const u16* vlb = vtl + (size_t)bh * HD * NN;

    const int w = tid >> 6, l = tid & 63;
    const int l15 = l & 15, kb4 = l >> 4;
    const int lrow = l >> 2, lch = (l & 3) * 8;

    f32x4 acc[2][4], accs[2];
    const f32x4 zero = {0.f, 0.f, 0.f, 0.f};
#pragma unroll
    for (int a = 0; a < 2; ++a) {
#pragma unroll
        for (int c = 0; c < 4; ++c) acc[a][c] = zero;
        accs[a] = zero;
    }
    s16x8 ones;
#pragma unroll
    for (int e = 0; e < 8; ++e) ones[e] = (short)0x3F80;   // bf16 1.0

    for (int k0 = 0; k0 < NN; k0 += 32) {
#pragma unroll
        for (int t = 0; t < 2; ++t) {
            const int r = w * 32 + t * 16;
            GLD16(&Mh[(size_t)(i0 + r + lrow) * NN + k0 + lch], &sM[r * 32]);
        }
        {
            const int r = w * 16;                  // V rows: 4 waves x 16 = 64
            const size_t vr = (size_t)(r + lrow) * NN + k0 + lch;
            GLD16(&vhb[vr], &sVh[r * 32]);
            GLD16(&vlb[vr], &sVl[r * 32]);
        }
        __syncthreads();

        s16x8 af[2], bh[4], bl[4];
#pragma unroll
        for (int f = 0; f < 2; ++f)
            af[f] = *(const s16x8*)&sM[(w * 32 + f * 16 + l15) * 32 + kb4 * 8];
#pragma unroll
        for (int f = 0; f < 4; ++f) {
            bh[f] = *(const s16x8*)&sVh[(f * 16 + l15) * 32 + kb4 * 8];
            bl[f] = *(const s16x8*)&sVl[(f * 16 + l15) * 32 + kb4 * 8];
        }
#pragma unroll
        for (int fr = 0; fr < 2; ++fr) {
#pragma unroll
            for (int fc = 0; fc < 4; ++fc) {
                acc[fr][fc] = __builtin_amdgcn_mfma_f32_16x16x32_bf16(
                    af[fr], bh[fc], acc[fr][fc], 0, 0, 0);
                acc[fr][fc] = __builtin_amdgcn_mfma_f32_16x16x32_bf16(
                    af[fr], bl[fc], acc[fr][fc], 0, 0, 0);
            }
            accs[fr] = __builtin_amdgcn_mfma_f32_16x16x32_bf16(
                af[fr], ones, accs[fr], 0, 0, 0);
        }
        __syncthreads();
    }

#pragma unroll
    for (int fr = 0; fr < 2; ++fr)
#pragma unroll
        for (int r = 0; r < 4; ++r) {
            const int gi = i0 + w * 32 + fr * 16 + kb4 * 4 + r;
            const float inv = 1.0f / (accs[fr][r] + 1e-9f);
            const size_t ob = (size_t)(b * NN + gi) * DIMC + h * HD;
#pragma unroll
            for (int fc = 0; fc < 4; ++fc) {
                const int gd = fc * 16 + l15;
                bfp s = splitf(acc[fr][fc][r] * inv);
                aoh[ob + gd] = s.h;
                aol[ob + gd] = s.l;
            }
        }
}

// ---------------------------------------------------------------------------
extern "C" void kernel_launch(void* const* d_in, const int* in_sizes, int n_in,
                              void* d_out, int out_size, void* d_ws, size_t ws_size,
                              hipStream_t stream)
{
    const float* x      = (const float*)d_in[0];
    const float* qkv_w  = (const float*)d_in[1];
    const float* qkv_b  = (const float*)d_in[2];
    const float* proj_w = (const float*)d_in[3];
    const float* proj_b = (const float*)d_in[4];
    const float* lamb   = (const float*)d_in[5];
    const float* gamma  = (const float*)d_in[6];
    const float* delta  = (const float*)d_in[7];

    char* p = (char*)d_ws;
    float* qkvb = (float*)p;                p += (size_t)4096 * QKVC * 4;
    u16* xh  = (u16*)p;                     p += (size_t)4096 * DIMC * 2;
    u16* xl  = (u16*)p;                     p += (size_t)4096 * DIMC * 2;
    u16* wh  = (u16*)p;                     p += (size_t)QKVC * DIMC * 2;
    u16* wl  = (u16*)p;                     p += (size_t)QKVC * DIMC * 2;
    u16* pwh = (u16*)p;                     p += (size_t)DIMC * DIMC * 2;
    u16* pwl = (u16*)p;                     p += (size_t)DIMC * DIMC * 2;
    u16* qh  = (u16*)p;                     p += (size_t)BHT * NN * HD * 2;
    u16* ql  = (u16*)p;                     p += (size_t)BHT * NN * HD * 2;
    u16* kh  = (u16*)p;                     p += (size_t)BHT * NN * HD * 2;
    u16* kl  = (u16*)p;                     p += (size_t)BHT * NN * HD * 2;
    u16* vth = (u16*)p;                     p += (size_t)BHT * HD * NN * 2;
    u16* vtl = (u16*)p;                     p += (size_t)BHT * HD * NN * 2;
    u16* aoh = (u16*)p;                     p += (size_t)4096 * DIMC * 2;
    u16* aol = (u16*)p;                     p += (size_t)4096 * DIMC * 2;
    const size_t fixed = (size_t)(p - (char*)d_ws);

    // per-head: S fp32 4MB (M bf16 aliases into it) + A 2MB + At 2MB
    const size_t perh = (size_t)NN * NN * 4 + 2 * (size_t)NN * NN * 2;
    static const int choices[] = {48, 24, 16, 12, 8, 6, 4, 3, 2, 1};
    int CH = 1;
    for (int ci = 0; ci < 10; ++ci) {
        int c = choices[ci];
        if (fixed + (size_t)c * perh <= ws_size) { CH = c; break; }
    }

    float* Sb = (float*)p;                  p += (size_t)CH * NN * NN * 4;
    u16* Abf  = (u16*)p;                    p += (size_t)CH * NN * NN * 2;
    u16* Atb  = (u16*)p;                    p += (size_t)CH * NN * NN * 2;
    u16* Mb   = (u16*)Sb;                   // alias: S dead after softmax

    // 0) splits of inputs
    split_f2b<<<dim3((4096 * DIMC / 4 + 255) / 256), 256, 0, stream>>>(x, xh, xl, 4096 * DIMC / 4);
    split_f2b<<<dim3((QKVC * DIMC / 4 + 255) / 256), 256, 0, stream>>>(qkv_w, wh, wl, QKVC * DIMC / 4);
    split_f2b<<<dim3((DIMC * DIMC / 4 + 255) / 256), 256, 0, stream>>>(proj_w, pwh, pwl, DIMC * DIMC / 4);

    // 1) qkv = x @ qkv_w^T + qkv_b
    gemm3_mfma<<<dim3(QKVC / 128, 4096 / 128), 256, 0, stream>>>(
        4096, QKVC, DIMC, xh, xl, wh, wl, qkv_b, qkvb);

    // 1b) per-head splits of q,k (scale folded) and v^T
    prep_qk<<<dim3(BHT, NN / 16), 256, 0, stream>>>(qkvb, qh, ql, kh, kl);
    prep_vt<<<dim3(NN / 64, BHT), 256, 0, stream>>>(qkvb, vth, vtl);

    // 2..5) per chunk of heads
    for (int h0 = 0; h0 < BHT; h0 += CH) {
        qk_mfma<<<dim3(8, 8, CH), 256, 0, stream>>>(qh, ql, kh, kl, Sb, h0);
        softmax_b<<<dim3(CH * NN), 256, 0, stream>>>(Sb, Abf);
        transpose_b2b<<<dim3(16, 16, CH), 256, 0, stream>>>(Abf, Atb);
        mpow_mfma<<<dim3(8, 8, CH), 256, 0, stream>>>(
            Abf, Atb, Mb, lamb, gamma, delta, h0);
        pv_mfma<<<dim3(8, CH), 256, 0, stream>>>(Mb, vth, vtl, aoh, aol, h0);
    }

    // 6) final = ao @ proj_w^T + proj_b
    gemm3_mfma<<<dim3(DIMC / 128, 4096 / 128), 256, 0, stream>>>(
        4096, DIMC, DIMC, aoh, aol, pwh, pwl, proj_b, (float*)d_out);
}

// Round 7
// 502.959 us; speedup vs baseline: 3.8001x; 1.0892x over previous
//
#include <hip/hip_runtime.h>
#include <hip/hip_bf16.h>

#define DIMC 768
#define NH 12
#define HD 64
#define BB 4
#define NN 1024
#define BHT 48          // BB*NH
#define QKVC 2304       // 3*DIM

typedef unsigned short u16;
typedef __attribute__((ext_vector_type(4))) unsigned short u16x4;
typedef __attribute__((ext_vector_type(8))) unsigned short u16x8;
typedef __attribute__((ext_vector_type(8))) short s16x8;
typedef __attribute__((ext_vector_type(4))) float f32x4;

// async global->LDS, 16B per lane; lds base must be wave-uniform.
#define GLD16(g, l) __builtin_amdgcn_global_load_lds( \
    (__attribute__((address_space(1))) void*)(g),     \
    (__attribute__((address_space(3))) void*)(l), 16, 0, 0)

__device__ __forceinline__ u16 f2bf(float f) {
    unsigned u = __float_as_uint(f);
    return (u16)((u + 0x7FFF + ((u >> 16) & 1)) >> 16);   // RNE
}
__device__ __forceinline__ float bf2f(u16 v) {
    return __uint_as_float(((unsigned)v) << 16);
}
struct bfp { u16 h, l; };
__device__ __forceinline__ bfp splitf(float f) {
    bfp r;
    r.h = f2bf(f);
    r.l = f2bf(f - bf2f(r.h));      // exact residual, bf16-rounded
    return r;
}

// ---------------------------------------------------------------------------
// Elementwise split: src fp32 -> (hi, lo) bf16. n multiple of 4.
// ---------------------------------------------------------------------------
__global__ __launch_bounds__(256) void split_f2b(
    const float* __restrict__ src, u16* __restrict__ hi, u16* __restrict__ lo,
    int n4)
{
    int idx = blockIdx.x * 256 + threadIdx.x;
    if (idx >= n4) return;
    float4 v = *(const float4*)&src[idx * 4];
    u16x4 h, l;
    bfp s;
    s = splitf(v.x); h[0] = s.h; l[0] = s.l;
    s = splitf(v.y); h[1] = s.h; l[1] = s.l;
    s = splitf(v.z); h[2] = s.h; l[2] = s.l;
    s = splitf(v.w); h[3] = s.h; l[3] = s.l;
    *(u16x4*)&hi[idx * 4] = h;
    *(u16x4*)&lo[idx * 4] = l;
}

// ---------------------------------------------------------------------------
// Generic split-bf16 GEMM: C = A @ B^T + bias (3-term MFMA). Used for proj.
// 128x128 tile, BK=32, 4 waves. global_load_lds staging.
// ---------------------------------------------------------------------------
__global__ __launch_bounds__(256) void gemm3_mfma(
    int Mrows, int Nout, int K,
    const u16* __restrict__ Ahp, const u16* __restrict__ Alp,
    const u16* __restrict__ Bhp, const u16* __restrict__ Blp,
    const float* __restrict__ bias, float* __restrict__ C)
{
    __shared__ alignas(16) u16 sAh[128 * 32], sAl[128 * 32], sBh[128 * 32], sBl[128 * 32];
    const int tid = threadIdx.x;
    const int j0 = blockIdx.x * 128, i0 = blockIdx.y * 128;
    const int w = tid >> 6, l = tid & 63;
    const int wr = w >> 1, wc = w & 1;
    const int l15 = l & 15, kb4 = l >> 4;
    const int lrow = l >> 2, lch = (l & 3) * 8;

    f32x4 acc[4][4];
    const f32x4 zero = {0.f, 0.f, 0.f, 0.f};
#pragma unroll
    for (int a = 0; a < 4; ++a)
#pragma unroll
        for (int b = 0; b < 4; ++b) acc[a][b] = zero;

    for (int k0 = 0; k0 < K; k0 += 32) {
#pragma unroll
        for (int t = 0; t < 2; ++t) {
            const int r = w * 32 + t * 16;
            const size_t ar = (size_t)(i0 + r + lrow) * K + k0 + lch;
            const size_t br = (size_t)(j0 + r + lrow) * K + k0 + lch;
            GLD16(&Ahp[ar], &sAh[r * 32]);
            GLD16(&Alp[ar], &sAl[r * 32]);
            GLD16(&Bhp[br], &sBh[r * 32]);
            GLD16(&Blp[br], &sBl[r * 32]);
        }
        __syncthreads();

        s16x8 ah[4], al[4], bh[4], bl[4];
#pragma unroll
        for (int f = 0; f < 4; ++f) {
            const int ao = (wr * 64 + f * 16 + l15) * 32 + kb4 * 8;
            const int bo = (wc * 64 + f * 16 + l15) * 32 + kb4 * 8;
            ah[f] = *(const s16x8*)&sAh[ao];
            al[f] = *(const s16x8*)&sAl[ao];
            bh[f] = *(const s16x8*)&sBh[bo];
            bl[f] = *(const s16x8*)&sBl[bo];
        }
#pragma unroll
        for (int fr = 0; fr < 4; ++fr)
#pragma unroll
            for (int fc = 0; fc < 4; ++fc) {
                acc[fr][fc] = __builtin_amdgcn_mfma_f32_16x16x32_bf16(
                    ah[fr], bh[fc], acc[fr][fc], 0, 0, 0);
                acc[fr][fc] = __builtin_amdgcn_mfma_f32_16x16x32_bf16(
                    ah[fr], bl[fc], acc[fr][fc], 0, 0, 0);
                acc[fr][fc] = __builtin_amdgcn_mfma_f32_16x16x32_bf16(
                    al[fr], bh[fc], acc[fr][fc], 0, 0, 0);
            }
        __syncthreads();
    }

#pragma unroll
    for (int fr = 0; fr < 4; ++fr)
#pragma unroll
        for (int r = 0; r < 4; ++r) {
            const int gi = i0 + wr * 64 + fr * 16 + kb4 * 4 + r;
#pragma unroll
            for (int fc = 0; fc < 4; ++fc) {
                const int gj = j0 + wc * 64 + fc * 16 + l15;
                C[(size_t)gi * Nout + gj] = acc[fr][fc][r] + bias[gj];
            }
        }
}

// ---------------------------------------------------------------------------
// qkv fused GEMM: qkv = x @ W^T + b, epilogue writes q/k (split, q scaled
// 0.125) in (bh,n,64) layout and v^T (split) in (bh,64,n) layout directly.
// Tile 128x128; part (q/k/v) is block-uniform since 128 | 768.
// ---------------------------------------------------------------------------
__global__ __launch_bounds__(256) void qkv_fused_mfma(
    const u16* __restrict__ Ahp, const u16* __restrict__ Alp,
    const u16* __restrict__ Bhp, const u16* __restrict__ Blp,
    const float* __restrict__ bias,
    u16* __restrict__ qh, u16* __restrict__ ql,
    u16* __restrict__ kh, u16* __restrict__ kl,
    u16* __restrict__ vth, u16* __restrict__ vtl)
{
    __shared__ alignas(16) u16 sAh[128 * 32], sAl[128 * 32], sBh[128 * 32], sBl[128 * 32];
    const int tid = threadIdx.x;
    const int j0 = blockIdx.x * 128, i0 = blockIdx.y * 128;
    const int w = tid >> 6, l = tid & 63;
    const int wr = w >> 1, wc = w & 1;
    const int l15 = l & 15, kb4 = l >> 4;
    const int lrow = l >> 2, lch = (l & 3) * 8;
    const int K = DIMC;

    f32x4 acc[4][4];
    const f32x4 zero = {0.f, 0.f, 0.f, 0.f};
#pragma unroll
    for (int a = 0; a < 4; ++a)
#pragma unroll
        for (int b = 0; b < 4; ++b) acc[a][b] = zero;

    for (int k0 = 0; k0 < K; k0 += 32) {
#pragma unroll
        for (int t = 0; t < 2; ++t) {
            const int r = w * 32 + t * 16;
            const size_t ar = (size_t)(i0 + r + lrow) * K + k0 + lch;
            const size_t br = (size_t)(j0 + r + lrow) * K + k0 + lch;
            GLD16(&Ahp[ar], &sAh[r * 32]);
            GLD16(&Alp[ar], &sAl[r * 32]);
            GLD16(&Bhp[br], &sBh[r * 32]);
            GLD16(&Blp[br], &sBl[r * 32]);
        }
        __syncthreads();

        s16x8 ah[4], al[4], bh[4], bl[4];
#pragma unroll
        for (int f = 0; f < 4; ++f) {
            const int ao = (wr * 64 + f * 16 + l15) * 32 + kb4 * 8;
            const int bo = (wc * 64 + f * 16 + l15) * 32 + kb4 * 8;
            ah[f] = *(const s16x8*)&sAh[ao];
            al[f] = *(const s16x8*)&sAl[ao];
            bh[f] = *(const s16x8*)&sBh[bo];
            bl[f] = *(const s16x8*)&sBl[bo];
        }
#pragma unroll
        for (int fr = 0; fr < 4; ++fr)
#pragma unroll
            for (int fc = 0; fc < 4; ++fc) {
                acc[fr][fc] = __builtin_amdgcn_mfma_f32_16x16x32_bf16(
                    ah[fr], bh[fc], acc[fr][fc], 0, 0, 0);
                acc[fr][fc] = __builtin_amdgcn_mfma_f32_16x16x32_bf16(
                    ah[fr], bl[fc], acc[fr][fc], 0, 0, 0);
                acc[fr][fc] = __builtin_amdgcn_mfma_f32_16x16x32_bf16(
                    al[fr], bh[fc], acc[fr][fc], 0, 0, 0);
            }
        __syncthreads();
    }

    const int part = j0 / DIMC;               // 0=q, 1=k, 2=v (block-uniform)
    const int hbase = (j0 % DIMC) >> 6;
    const int h = hbase + wc;

#pragma unroll
    for (int fr = 0; fr < 4; ++fr) {
        const int rowbase = i0 + wr * 64 + fr * 16 + kb4 * 4;
        const int b = rowbase >> 10;
        const int n0 = rowbase & 1023;
        const int bh = b * NH + h;
#pragma unroll
        for (int fc = 0; fc < 4; ++fc) {
            const int gj = j0 + wc * 64 + fc * 16 + l15;
            const float bv = bias[gj];
            const int d = fc * 16 + l15;
            if (part == 0) {
#pragma unroll
                for (int r = 0; r < 4; ++r) {
                    bfp s = splitf((acc[fr][fc][r] + bv) * 0.125f);
                    const size_t o = ((size_t)bh * NN + n0 + r) * HD + d;
                    qh[o] = s.h; ql[o] = s.l;
                }
            } else if (part == 1) {
#pragma unroll
                for (int r = 0; r < 4; ++r) {
                    bfp s = splitf(acc[fr][fc][r] + bv);
                    const size_t o = ((size_t)bh * NN + n0 + r) * HD + d;
                    kh[o] = s.h; kl[o] = s.l;
                }
            } else {
                u16x4 hv, lv;
#pragma unroll
                for (int r = 0; r < 4; ++r) {
                    bfp s = splitf(acc[fr][fc][r] + bv);
                    hv[r] = s.h; lv[r] = s.l;
                }
                const size_t o = ((size_t)bh * HD + d) * NN + n0;
                *(u16x4*)&vth[o] = hv;
                *(u16x4*)&vtl[o] = lv;
            }
        }
    }
}

// ---------------------------------------------------------------------------
// qk_mfma: S = (q*0.125) @ k^T per head, split 3-term. K=64.
// grid (8, 8, CH). Output S fp32. global_load_lds staging.
// ---------------------------------------------------------------------------
__global__ __launch_bounds__(256) void qk_mfma(
    const u16* __restrict__ qh, const u16* __restrict__ ql,
    const u16* __restrict__ kh, const u16* __restrict__ kl,
    float* __restrict__ Sb, int h0)
{
    __shared__ alignas(16) u16 sAh[128 * 32], sAl[128 * 32], sBh[128 * 32], sBl[128 * 32];
    const int tid = threadIdx.x;
    const int j0 = blockIdx.x * 128, i0 = blockIdx.y * 128;
    const int bhl = blockIdx.z;
    const int bh = h0 + bhl;
    const int w = tid >> 6, l = tid & 63;
    const int wr = w >> 1, wc = w & 1;
    const int l15 = l & 15, kb4 = l >> 4;
    const int lrow = l >> 2, lch = (l & 3) * 8;

    f32x4 acc[4][4];
    const f32x4 zero = {0.f, 0.f, 0.f, 0.f};
#pragma unroll
    for (int a = 0; a < 4; ++a)
#pragma unroll
        for (int b = 0; b < 4; ++b) acc[a][b] = zero;

    for (int k0 = 0; k0 < HD; k0 += 32) {
#pragma unroll
        for (int t = 0; t < 2; ++t) {
            const int r = w * 32 + t * 16;
            const size_t ar = ((size_t)bh * NN + i0 + r + lrow) * HD + k0 + lch;
            const size_t br = ((size_t)bh * NN + j0 + r + lrow) * HD + k0 + lch;
            GLD16(&qh[ar], &sAh[r * 32]);
            GLD16(&ql[ar], &sAl[r * 32]);
            GLD16(&kh[br], &sBh[r * 32]);
            GLD16(&kl[br], &sBl[r * 32]);
        }
        __syncthreads();

        s16x8 ah[4], al[4], bh[4], bl[4];
#pragma unroll
        for (int f = 0; f < 4; ++f) {
            const int ao = (wr * 64 + f * 16 + l15) * 32 + kb4 * 8;
            const int bo = (wc * 64 + f * 16 + l15) * 32 + kb4 * 8;
            ah[f] = *(const s16x8*)&sAh[ao];
            al[f] = *(const s16x8*)&sAl[ao];
            bh[f] = *(const s16x8*)&sBh[bo];
            bl[f] = *(const s16x8*)&sBl[bo];
        }
#pragma unroll
        for (int fr = 0; fr < 4; ++fr)
#pragma unroll
            for (int fc = 0; fc < 4; ++fc) {
                acc[fr][fc] = __builtin_amdgcn_mfma_f32_16x16x32_bf16(
                    ah[fr], bh[fc], acc[fr][fc], 0, 0, 0);
                acc[fr][fc] = __builtin_amdgcn_mfma_f32_16x16x32_bf16(
                    ah[fr], bl[fc], acc[fr][fc], 0, 0, 0);
                acc[fr][fc] = __builtin_amdgcn_mfma_f32_16x16x32_bf16(
                    al[fr], bh[fc], acc[fr][fc], 0, 0, 0);
            }
        __syncthreads();
    }

    float* Sh = Sb + (size_t)bhl * NN * NN;
#pragma unroll
    for (int fr = 0; fr < 4; ++fr)
#pragma unroll
        for (int r = 0; r < 4; ++r) {
            const int gi = i0 + wr * 64 + fr * 16 + kb4 * 4 + r;
#pragma unroll
            for (int fc = 0; fc < 4; ++fc) {
                const int gj = j0 + wc * 64 + fc * 16 + l15;
                Sh[(size_t)gi * NN + gj] = acc[fr][fc][r];
            }
        }
}

// ---------------------------------------------------------------------------
// softmax: read S fp32 row, write A bf16 row. grid CH*NN blocks of 256.
// ---------------------------------------------------------------------------
__global__ __launch_bounds__(256) void softmax_b(
    const float* __restrict__ Sb, u16* __restrict__ Abf)
{
    const int row = blockIdx.x;
    const float* p = Sb + (size_t)row * NN;
    u16* q = Abf + (size_t)row * NN;
    const int tid = threadIdx.x;
    __shared__ float redm[4], reds[4];

    float4 v = *(const float4*)&p[tid * 4];
    float m = fmaxf(fmaxf(v.x, v.y), fmaxf(v.z, v.w));
#pragma unroll
    for (int off = 32; off >= 1; off >>= 1) m = fmaxf(m, __shfl_xor(m, off));
    if ((tid & 63) == 0) redm[tid >> 6] = m;
    __syncthreads();
    m = fmaxf(fmaxf(redm[0], redm[1]), fmaxf(redm[2], redm[3]));

    v.x = expf(v.x - m); v.y = expf(v.y - m);
    v.z = expf(v.z - m); v.w = expf(v.w - m);
    float s = v.x + v.y + v.z + v.w;
#pragma unroll
    for (int off = 32; off >= 1; off >>= 1) s += __shfl_xor(s, off);
    if ((tid & 63) == 0) reds[tid >> 6] = s;
    __syncthreads();
    s = reds[0] + reds[1] + reds[2] + reds[3];

    const float inv = 1.0f / s;
    u16x4 o;
    o[0] = f2bf(v.x * inv); o[1] = f2bf(v.y * inv);
    o[2] = f2bf(v.z * inv); o[3] = f2bf(v.w * inv);
    *(u16x4*)&q[tid * 4] = o;
}

// ---------------------------------------------------------------------------
// mpow: P = A@A (bf16 MFMA); M = relu(del*I + c1*A + c2*P) -> bf16.
// B-operand staged by in-kernel transpose of A's k-rows (no At buffer).
// grid (8, 8, CH), 128x128 tile, BK=32.
// ---------------------------------------------------------------------------
__global__ __launch_bounds__(256) void mpow_mfma(
    const u16* __restrict__ Abf, u16* __restrict__ Mb,
    const float* __restrict__ lamb, const float* __restrict__ gamma,
    const float* __restrict__ delta, int h0)
{
    __shared__ alignas(16) u16 sA[128 * 32], sB[128 * 32];
    const int tid = threadIdx.x;
    const int j0 = blockIdx.x * 128, i0 = blockIdx.y * 128;
    const int bz = blockIdx.z;
    const int h = (h0 + bz) % NH;
    const u16* Ah = Abf + (size_t)bz * NN * NN;

    const int w = tid >> 6, l = tid & 63;
    const int wr = w >> 1, wc = w & 1;
    const int l15 = l & 15, kb4 = l >> 4;
    const int lrow = l >> 2, lch = (l & 3) * 8;
    // B transpose staging map: 256 threads cover 32 k-rows x 128 j-cols
    const int kr = tid & 31;
    const int jc = (tid >> 5) * 16;

    f32x4 acc[4][4];
    const f32x4 zero = {0.f, 0.f, 0.f, 0.f};
#pragma unroll
    for (int a = 0; a < 4; ++a)
#pragma unroll
        for (int b = 0; b < 4; ++b) acc[a][b] = zero;

    for (int k0 = 0; k0 < NN; k0 += 32) {
        // A-side: async direct to LDS
#pragma unroll
        for (int t = 0; t < 2; ++t) {
            const int r = w * 32 + t * 16;
            GLD16(&Ah[(size_t)(i0 + r + lrow) * NN + k0 + lch], &sA[r * 32]);
        }
        // B-side: read A's k-rows (coalesced), write transposed [j][k]
        {
            const u16* arow = &Ah[(size_t)(k0 + kr) * NN + j0 + jc];
            u16x8 b0 = *(const u16x8*)arow;
            u16x8 b1 = *(const u16x8*)(arow + 8);
#pragma unroll
            for (int e = 0; e < 8; ++e) {
                sB[(jc + e) * 32 + kr]     = b0[e];
                sB[(jc + 8 + e) * 32 + kr] = b1[e];
            }
        }
        __syncthreads();

        s16x8 af[4], bf[4];
#pragma unroll
        for (int f = 0; f < 4; ++f) {
            af[f] = *(const s16x8*)&sA[(wr * 64 + f * 16 + l15) * 32 + kb4 * 8];
            bf[f] = *(const s16x8*)&sB[(wc * 64 + f * 16 + l15) * 32 + kb4 * 8];
        }
#pragma unroll
        for (int fr = 0; fr < 4; ++fr)
#pragma unroll
            for (int fc = 0; fc < 4; ++fc)
                acc[fr][fc] = __builtin_amdgcn_mfma_f32_16x16x32_bf16(
                    af[fr], bf[fc], acc[fr][fc], 0, 0, 0);
        __syncthreads();
    }

    const float lam = lamb[h];
    const float c1 = gamma[h] - 6.0f * lam;
    const float c2 = 7.0f * lam;
    const float del = delta[h];
    u16* Mh = Mb + (size_t)bz * NN * NN;

#pragma unroll
    for (int fr = 0; fr < 4; ++fr)
#pragma unroll
        for (int r = 0; r < 4; ++r) {
            const int gi = i0 + wr * 64 + fr * 16 + kb4 * 4 + r;
#pragma unroll
            for (int fc = 0; fc < 4; ++fc) {
                const int gj = j0 + wc * 64 + fc * 16 + l15;
                const float a = bf2f(Ah[(size_t)gi * NN + gj]);
                float m = c2 * acc[fr][fc][r] + c1 * a + (gi == gj ? del : 0.f);
                m = fmaxf(m, 0.f);
                Mh[(size_t)gi * NN + gj] = f2bf(m);
            }
        }
}

// ---------------------------------------------------------------------------
// pv: ao = (M @ V) / rowsum(M). V as v^T hi/lo (2-term split); rowsum via
// ones-fragment MFMA. grid (8 i-tiles, CH). Writes ao hi/lo.
// ---------------------------------------------------------------------------
__global__ __launch_bounds__(256) void pv_mfma(
    const u16* __restrict__ Mb,
    const u16* __restrict__ vth, const u16* __restrict__ vtl,
    u16* __restrict__ aoh, u16* __restrict__ aol, int h0)
{
    __shared__ alignas(16) u16 sM[128 * 32], sVh[64 * 32], sVl[64 * 32];
    const int tid = threadIdx.x;
    const int i0 = blockIdx.x * 128;
    const int bhl = blockIdx.y;
    const int bh = h0 + bhl;
    const int b = bh / NH, h = bh % NH;
    const u16* Mh = Mb + (size_t)bhl * NN * NN;
    const u16* vhb = vth + (size_t)bh * HD * NN;
    const u16* vlb = vtl + (size_t)bh * HD * NN;

    const int w = tid >> 6, l = tid & 63;
    const int l15 = l & 15, kb4 = l >> 4;
    const int lrow = l >> 2, lch = (l & 3) * 8;

    f32x4 acc[2][4], accs[2];
    const f32x4 zero = {0.f, 0.f, 0.f, 0.f};
#pragma unroll
    for (int a = 0; a < 2; ++a) {
#pragma unroll
        for (int c = 0; c < 4; ++c) acc[a][c] = zero;
        accs[a] = zero;
    }
    s16x8 ones;
#pragma unroll
    for (int e = 0; e < 8; ++e) ones[e] = (short)0x3F80;   // bf16 1.0

    for (int k0 = 0; k0 < NN; k0 += 32) {
#pragma unroll
        for (int t = 0; t < 2; ++t) {
            const int r = w * 32 + t * 16;
            GLD16(&Mh[(size_t)(i0 + r + lrow) * NN + k0 + lch], &sM[r * 32]);
        }
        {
            const int r = w * 16;                  // V rows: 4 waves x 16 = 64
            const size_t vr = (size_t)(r + lrow) * NN + k0 + lch;
            GLD16(&vhb[vr], &sVh[r * 32]);
            GLD16(&vlb[vr], &sVl[r * 32]);
        }
        __syncthreads();

        s16x8 af[2], bh[4], bl[4];
#pragma unroll
        for (int f = 0; f < 2; ++f)
            af[f] = *(const s16x8*)&sM[(w * 32 + f * 16 + l15) * 32 + kb4 * 8];
#pragma unroll
        for (int f = 0; f < 4; ++f) {
            bh[f] = *(const s16x8*)&sVh[(f * 16 + l15) * 32 + kb4 * 8];
            bl[f] = *(const s16x8*)&sVl[(f * 16 + l15) * 32 + kb4 * 8];
        }
#pragma unroll
        for (int fr = 0; fr < 2; ++fr) {
#pragma unroll
            for (int fc = 0; fc < 4; ++fc) {
                acc[fr][fc] = __builtin_amdgcn_mfma_f32_16x16x32_bf16(
                    af[fr], bh[fc], acc[fr][fc], 0, 0, 0);
                acc[fr][fc] = __builtin_amdgcn_mfma_f32_16x16x32_bf16(
                    af[fr], bl[fc], acc[fr][fc], 0, 0, 0);
            }
            accs[fr] = __builtin_amdgcn_mfma_f32_16x16x32_bf16(
                af[fr], ones, accs[fr], 0, 0, 0);
        }
        __syncthreads();
    }

#pragma unroll
    for (int fr = 0; fr < 2; ++fr)
#pragma unroll
        for (int r = 0; r < 4; ++r) {
            const int gi = i0 + w * 32 + fr * 16 + kb4 * 4 + r;
            const float inv = 1.0f / (accs[fr][r] + 1e-9f);
            const size_t ob = (size_t)(b * NN + gi) * DIMC + h * HD;
#pragma unroll
            for (int fc = 0; fc < 4; ++fc) {
                const int gd = fc * 16 + l15;
                bfp s = splitf(acc[fr][fc][r] * inv);
                aoh[ob + gd] = s.h;
                aol[ob + gd] = s.l;
            }
        }
}

// ---------------------------------------------------------------------------
extern "C" void kernel_launch(void* const* d_in, const int* in_sizes, int n_in,
                              void* d_out, int out_size, void* d_ws, size_t ws_size,
                              hipStream_t stream)
{
    const float* x      = (const float*)d_in[0];
    const float* qkv_w  = (const float*)d_in[1];
    const float* qkv_b  = (const float*)d_in[2];
    const float* proj_w = (const float*)d_in[3];
    const float* proj_b = (const float*)d_in[4];
    const float* lamb   = (const float*)d_in[5];
    const float* gamma  = (const float*)d_in[6];
    const float* delta  = (const float*)d_in[7];

    char* p = (char*)d_ws;
    u16* xh  = (u16*)p;                     p += (size_t)4096 * DIMC * 2;
    u16* xl  = (u16*)p;                     p += (size_t)4096 * DIMC * 2;
    u16* wh  = (u16*)p;                     p += (size_t)QKVC * DIMC * 2;
    u16* wl  = (u16*)p;                     p += (size_t)QKVC * DIMC * 2;
    u16* pwh = (u16*)p;                     p += (size_t)DIMC * DIMC * 2;
    u16* pwl = (u16*)p;                     p += (size_t)DIMC * DIMC * 2;
    u16* qh  = (u16*)p;                     p += (size_t)BHT * NN * HD * 2;
    u16* ql  = (u16*)p;                     p += (size_t)BHT * NN * HD * 2;
    u16* kh  = (u16*)p;                     p += (size_t)BHT * NN * HD * 2;
    u16* kl  = (u16*)p;                     p += (size_t)BHT * NN * HD * 2;
    u16* vth = (u16*)p;                     p += (size_t)BHT * HD * NN * 2;
    u16* vtl = (u16*)p;                     p += (size_t)BHT * HD * NN * 2;
    u16* aoh = (u16*)p;                     p += (size_t)4096 * DIMC * 2;
    u16* aol = (u16*)p;                     p += (size_t)4096 * DIMC * 2;
    const size_t fixed = (size_t)(p - (char*)d_ws);

    // per-head: S fp32 4MB (M bf16 aliases into it) + A bf16 2MB
    const size_t perh = (size_t)NN * NN * 4 + (size_t)NN * NN * 2;
    static const int choices[] = {48, 24, 16, 12, 8, 6, 4, 3, 2, 1};
    int CH = 1;
    for (int ci = 0; ci < 10; ++ci) {
        int c = choices[ci];
        if (fixed + (size_t)c * perh <= ws_size) { CH = c; break; }
    }

    float* Sb = (float*)p;                  p += (size_t)CH * NN * NN * 4;
    u16* Abf  = (u16*)p;                    p += (size_t)CH * NN * NN * 2;
    u16* Mb   = (u16*)Sb;                   // alias: S dead after softmax

    // 0) splits of inputs
    split_f2b<<<dim3((4096 * DIMC / 4 + 255) / 256), 256, 0, stream>>>(x, xh, xl, 4096 * DIMC / 4);
    split_f2b<<<dim3((QKVC * DIMC / 4 + 255) / 256), 256, 0, stream>>>(qkv_w, wh, wl, QKVC * DIMC / 4);
    split_f2b<<<dim3((DIMC * DIMC / 4 + 255) / 256), 256, 0, stream>>>(proj_w, pwh, pwl, DIMC * DIMC / 4);

    // 1) qkv GEMM fused: writes qh/ql/kh/kl (bh,n,64) and vth/vtl (bh,64,n)
    qkv_fused_mfma<<<dim3(QKVC / 128, 4096 / 128), 256, 0, stream>>>(
        xh, xl, wh, wl, qkv_b, qh, ql, kh, kl, vth, vtl);

    // 2..5) per chunk of heads
    for (int h0 = 0; h0 < BHT; h0 += CH) {
        qk_mfma<<<dim3(8, 8, CH), 256, 0, stream>>>(qh, ql, kh, kl, Sb, h0);
        softmax_b<<<dim3(CH * NN), 256, 0, stream>>>(Sb, Abf);
        mpow_mfma<<<dim3(8, 8, CH), 256, 0, stream>>>(
            Abf, Mb, lamb, gamma, delta, h0);
        pv_mfma<<<dim3(8, CH), 256, 0, stream>>>(Mb, vth, vtl, aoh, aol, h0);
    }

    // 6) final = ao @ proj_w^T + proj_b
    gemm3_mfma<<<dim3(DIMC / 128, 4096 / 128), 256, 0, stream>>>(
        4096, DIMC, DIMC, aoh, aol, pwh, pwl, proj_b, (float*)d_out);
}

// Round 8
// 439.381 us; speedup vs baseline: 4.3499x; 1.1447x over previous
//
#include <hip/hip_runtime.h>
#include <hip/hip_bf16.h>

#define DIMC 768
#define NH 12
#define HD 64
#define BB 4
#define NN 1024
#define BHT 48          // BB*NH
#define QKVC 2304       // 3*DIM

typedef unsigned short u16;
typedef __attribute__((ext_vector_type(4))) unsigned short u16x4;
typedef __attribute__((ext_vector_type(8))) unsigned short u16x8;
typedef __attribute__((ext_vector_type(8))) short s16x8;
typedef __attribute__((ext_vector_type(4))) float f32x4;

// async global->LDS, 16B per lane; lds base must be wave-uniform.
#define GLD16(g, l) __builtin_amdgcn_global_load_lds( \
    (__attribute__((address_space(1))) void*)(g),     \
    (__attribute__((address_space(3))) void*)(l), 16, 0, 0)

__device__ __forceinline__ u16 f2bf(float f) {
    unsigned u = __float_as_uint(f);
    return (u16)((u + 0x7FFF + ((u >> 16) & 1)) >> 16);   // RNE
}
__device__ __forceinline__ float bf2f(u16 v) {
    return __uint_as_float(((unsigned)v) << 16);
}
struct bfp { u16 h, l; };
__device__ __forceinline__ bfp splitf(float f) {
    bfp r;
    r.h = f2bf(f);
    r.l = f2bf(f - bf2f(r.h));      // exact residual, bf16-rounded
    return r;
}

// Bijective XCD swizzle (m204 form): valid when nwg % 8 == 0 (all our grids).
// Consecutive ORIGINAL ids round-robin over 8 XCDs; after remap each XCD gets
// a CONTIGUOUS run of work ids -> per-XCD L2 working set becomes one head.
__device__ __forceinline__ int swz_linear() {
    const int nwg = gridDim.x * gridDim.y * gridDim.z;
    const int L = blockIdx.x + gridDim.x * (blockIdx.y + gridDim.y * blockIdx.z);
    return (L & 7) * (nwg >> 3) + (L >> 3);
}

// ---------------------------------------------------------------------------
// Elementwise split: src fp32 -> (hi, lo) bf16. n multiple of 4.
// ---------------------------------------------------------------------------
__global__ __launch_bounds__(256) void split_f2b(
    const float* __restrict__ src, u16* __restrict__ hi, u16* __restrict__ lo,
    int n4)
{
    int idx = blockIdx.x * 256 + threadIdx.x;
    if (idx >= n4) return;
    float4 v = *(const float4*)&src[idx * 4];
    u16x4 h, l;
    bfp s;
    s = splitf(v.x); h[0] = s.h; l[0] = s.l;
    s = splitf(v.y); h[1] = s.h; l[1] = s.l;
    s = splitf(v.z); h[2] = s.h; l[2] = s.l;
    s = splitf(v.w); h[3] = s.h; l[3] = s.l;
    *(u16x4*)&hi[idx * 4] = h;
    *(u16x4*)&lo[idx * 4] = l;
}

// ---------------------------------------------------------------------------
// Generic split-bf16 GEMM: C = A @ B^T + bias (3-term MFMA). Used for proj.
// 128x128 tile, BK=32, 4 waves. global_load_lds staging. XCD swizzle.
// ---------------------------------------------------------------------------
__global__ __launch_bounds__(256) void gemm3_mfma(
    int Mrows, int Nout, int K,
    const u16* __restrict__ Ahp, const u16* __restrict__ Alp,
    const u16* __restrict__ Bhp, const u16* __restrict__ Blp,
    const float* __restrict__ bias, float* __restrict__ C)
{
    __shared__ alignas(16) u16 sAh[128 * 32], sAl[128 * 32], sBh[128 * 32], sBl[128 * 32];
    const int tid = threadIdx.x;
    const int W = swz_linear();
    const int j0 = (W % gridDim.x) * 128, i0 = (W / gridDim.x) * 128;
    const int w = tid >> 6, l = tid & 63;
    const int wr = w >> 1, wc = w & 1;
    const int l15 = l & 15, kb4 = l >> 4;
    const int lrow = l >> 2, lch = (l & 3) * 8;

    f32x4 acc[4][4];
    const f32x4 zero = {0.f, 0.f, 0.f, 0.f};
#pragma unroll
    for (int a = 0; a < 4; ++a)
#pragma unroll
        for (int b = 0; b < 4; ++b) acc[a][b] = zero;

    for (int k0 = 0; k0 < K; k0 += 32) {
#pragma unroll
        for (int t = 0; t < 2; ++t) {
            const int r = w * 32 + t * 16;
            const size_t ar = (size_t)(i0 + r + lrow) * K + k0 + lch;
            const size_t br = (size_t)(j0 + r + lrow) * K + k0 + lch;
            GLD16(&Ahp[ar], &sAh[r * 32]);
            GLD16(&Alp[ar], &sAl[r * 32]);
            GLD16(&Bhp[br], &sBh[r * 32]);
            GLD16(&Blp[br], &sBl[r * 32]);
        }
        __syncthreads();

        s16x8 ah[4], al[4], bh[4], bl[4];
#pragma unroll
        for (int f = 0; f < 4; ++f) {
            const int ao = (wr * 64 + f * 16 + l15) * 32 + kb4 * 8;
            const int bo = (wc * 64 + f * 16 + l15) * 32 + kb4 * 8;
            ah[f] = *(const s16x8*)&sAh[ao];
            al[f] = *(const s16x8*)&sAl[ao];
            bh[f] = *(const s16x8*)&sBh[bo];
            bl[f] = *(const s16x8*)&sBl[bo];
        }
#pragma unroll
        for (int fr = 0; fr < 4; ++fr)
#pragma unroll
            for (int fc = 0; fc < 4; ++fc) {
                acc[fr][fc] = __builtin_amdgcn_mfma_f32_16x16x32_bf16(
                    ah[fr], bh[fc], acc[fr][fc], 0, 0, 0);
                acc[fr][fc] = __builtin_amdgcn_mfma_f32_16x16x32_bf16(
                    ah[fr], bl[fc], acc[fr][fc], 0, 0, 0);
                acc[fr][fc] = __builtin_amdgcn_mfma_f32_16x16x32_bf16(
                    al[fr], bh[fc], acc[fr][fc], 0, 0, 0);
            }
        __syncthreads();
    }

#pragma unroll
    for (int fr = 0; fr < 4; ++fr)
#pragma unroll
        for (int r = 0; r < 4; ++r) {
            const int gi = i0 + wr * 64 + fr * 16 + kb4 * 4 + r;
#pragma unroll
            for (int fc = 0; fc < 4; ++fc) {
                const int gj = j0 + wc * 64 + fc * 16 + l15;
                C[(size_t)gi * Nout + gj] = acc[fr][fc][r] + bias[gj];
            }
        }
}

// ---------------------------------------------------------------------------
// qkv fused GEMM: qkv = x @ W^T + b, epilogue writes q/k (split, q scaled
// 0.125) in (bh,n,64) layout and v^T (split) in (bh,64,n) layout directly.
// ---------------------------------------------------------------------------
__global__ __launch_bounds__(256) void qkv_fused_mfma(
    const u16* __restrict__ Ahp, const u16* __restrict__ Alp,
    const u16* __restrict__ Bhp, const u16* __restrict__ Blp,
    const float* __restrict__ bias,
    u16* __restrict__ qh, u16* __restrict__ ql,
    u16* __restrict__ kh, u16* __restrict__ kl,
    u16* __restrict__ vth, u16* __restrict__ vtl)
{
    __shared__ alignas(16) u16 sAh[128 * 32], sAl[128 * 32], sBh[128 * 32], sBl[128 * 32];
    const int tid = threadIdx.x;
    const int W = swz_linear();
    const int j0 = (W % gridDim.x) * 128, i0 = (W / gridDim.x) * 128;
    const int w = tid >> 6, l = tid & 63;
    const int wr = w >> 1, wc = w & 1;
    const int l15 = l & 15, kb4 = l >> 4;
    const int lrow = l >> 2, lch = (l & 3) * 8;
    const int K = DIMC;

    f32x4 acc[4][4];
    const f32x4 zero = {0.f, 0.f, 0.f, 0.f};
#pragma unroll
    for (int a = 0; a < 4; ++a)
#pragma unroll
        for (int b = 0; b < 4; ++b) acc[a][b] = zero;

    for (int k0 = 0; k0 < K; k0 += 32) {
#pragma unroll
        for (int t = 0; t < 2; ++t) {
            const int r = w * 32 + t * 16;
            const size_t ar = (size_t)(i0 + r + lrow) * K + k0 + lch;
            const size_t br = (size_t)(j0 + r + lrow) * K + k0 + lch;
            GLD16(&Ahp[ar], &sAh[r * 32]);
            GLD16(&Alp[ar], &sAl[r * 32]);
            GLD16(&Bhp[br], &sBh[r * 32]);
            GLD16(&Blp[br], &sBl[r * 32]);
        }
        __syncthreads();

        s16x8 ah[4], al[4], bh[4], bl[4];
#pragma unroll
        for (int f = 0; f < 4; ++f) {
            const int ao = (wr * 64 + f * 16 + l15) * 32 + kb4 * 8;
            const int bo = (wc * 64 + f * 16 + l15) * 32 + kb4 * 8;
            ah[f] = *(const s16x8*)&sAh[ao];
            al[f] = *(const s16x8*)&sAl[ao];
            bh[f] = *(const s16x8*)&sBh[bo];
            bl[f] = *(const s16x8*)&sBl[bo];
        }
#pragma unroll
        for (int fr = 0; fr < 4; ++fr)
#pragma unroll
            for (int fc = 0; fc < 4; ++fc) {
                acc[fr][fc] = __builtin_amdgcn_mfma_f32_16x16x32_bf16(
                    ah[fr], bh[fc], acc[fr][fc], 0, 0, 0);
                acc[fr][fc] = __builtin_amdgcn_mfma_f32_16x16x32_bf16(
                    ah[fr], bl[fc], acc[fr][fc], 0, 0, 0);
                acc[fr][fc] = __builtin_amdgcn_mfma_f32_16x16x32_bf16(
                    al[fr], bh[fc], acc[fr][fc], 0, 0, 0);
            }
        __syncthreads();
    }

    const int part = j0 / DIMC;               // 0=q, 1=k, 2=v (block-uniform)
    const int hbase = (j0 % DIMC) >> 6;
    const int h = hbase + wc;

#pragma unroll
    for (int fr = 0; fr < 4; ++fr) {
        const int rowbase = i0 + wr * 64 + fr * 16 + kb4 * 4;
        const int b = rowbase >> 10;
        const int n0 = rowbase & 1023;
        const int bh = b * NH + h;
#pragma unroll
        for (int fc = 0; fc < 4; ++fc) {
            const int gj = j0 + wc * 64 + fc * 16 + l15;
            const float bv = bias[gj];
            const int d = fc * 16 + l15;
            if (part == 0) {
#pragma unroll
                for (int r = 0; r < 4; ++r) {
                    bfp s = splitf((acc[fr][fc][r] + bv) * 0.125f);
                    const size_t o = ((size_t)bh * NN + n0 + r) * HD + d;
                    qh[o] = s.h; ql[o] = s.l;
                }
            } else if (part == 1) {
#pragma unroll
                for (int r = 0; r < 4; ++r) {
                    bfp s = splitf(acc[fr][fc][r] + bv);
                    const size_t o = ((size_t)bh * NN + n0 + r) * HD + d;
                    kh[o] = s.h; kl[o] = s.l;
                }
            } else {
                u16x4 hv, lv;
#pragma unroll
                for (int r = 0; r < 4; ++r) {
                    bfp s = splitf(acc[fr][fc][r] + bv);
                    hv[r] = s.h; lv[r] = s.l;
                }
                const size_t o = ((size_t)bh * HD + d) * NN + n0;
                *(u16x4*)&vth[o] = hv;
                *(u16x4*)&vtl[o] = lv;
            }
        }
    }
}

// ---------------------------------------------------------------------------
// qk_mfma: S = (q*0.125) @ k^T per head, split 3-term. K=64.
// grid (8, 8, CH). XCD swizzle: one head per XCD run.
// ---------------------------------------------------------------------------
__global__ __launch_bounds__(256) void qk_mfma(
    const u16* __restrict__ qh, const u16* __restrict__ ql,
    const u16* __restrict__ kh, const u16* __restrict__ kl,
    float* __restrict__ Sb, int h0)
{
    __shared__ alignas(16) u16 sAh[128 * 32], sAl[128 * 32], sBh[128 * 32], sBl[128 * 32];
    const int tid = threadIdx.x;
    const int W = swz_linear();
    const int bhl = W >> 6;
    const int ib = W & 63;
    const int j0 = (ib & 7) * 128, i0 = (ib >> 3) * 128;
    const int bh = h0 + bhl;
    const int w = tid >> 6, l = tid & 63;
    const int wr = w >> 1, wc = w & 1;
    const int l15 = l & 15, kb4 = l >> 4;
    const int lrow = l >> 2, lch = (l & 3) * 8;

    f32x4 acc[4][4];
    const f32x4 zero = {0.f, 0.f, 0.f, 0.f};
#pragma unroll
    for (int a = 0; a < 4; ++a)
#pragma unroll
        for (int b = 0; b < 4; ++b) acc[a][b] = zero;

    for (int k0 = 0; k0 < HD; k0 += 32) {
#pragma unroll
        for (int t = 0; t < 2; ++t) {
            const int r = w * 32 + t * 16;
            const size_t ar = ((size_t)bh * NN + i0 + r + lrow) * HD + k0 + lch;
            const size_t br = ((size_t)bh * NN + j0 + r + lrow) * HD + k0 + lch;
            GLD16(&qh[ar], &sAh[r * 32]);
            GLD16(&ql[ar], &sAl[r * 32]);
            GLD16(&kh[br], &sBh[r * 32]);
            GLD16(&kl[br], &sBl[r * 32]);
        }
        __syncthreads();

        s16x8 ah[4], al[4], bh[4], bl[4];
#pragma unroll
        for (int f = 0; f < 4; ++f) {
            const int ao = (wr * 64 + f * 16 + l15) * 32 + kb4 * 8;
            const int bo = (wc * 64 + f * 16 + l15) * 32 + kb4 * 8;
            ah[f] = *(const s16x8*)&sAh[ao];
            al[f] = *(const s16x8*)&sAl[ao];
            bh[f] = *(const s16x8*)&sBh[bo];
            bl[f] = *(const s16x8*)&sBl[bo];
        }
#pragma unroll
        for (int fr = 0; fr < 4; ++fr)
#pragma unroll
            for (int fc = 0; fc < 4; ++fc) {
                acc[fr][fc] = __builtin_amdgcn_mfma_f32_16x16x32_bf16(
                    ah[fr], bh[fc], acc[fr][fc], 0, 0, 0);
                acc[fr][fc] = __builtin_amdgcn_mfma_f32_16x16x32_bf16(
                    ah[fr], bl[fc], acc[fr][fc], 0, 0, 0);
                acc[fr][fc] = __builtin_amdgcn_mfma_f32_16x16x32_bf16(
                    al[fr], bh[fc], acc[fr][fc], 0, 0, 0);
            }
        __syncthreads();
    }

    float* Sh = Sb + (size_t)bhl * NN * NN;
#pragma unroll
    for (int fr = 0; fr < 4; ++fr)
#pragma unroll
        for (int r = 0; r < 4; ++r) {
            const int gi = i0 + wr * 64 + fr * 16 + kb4 * 4 + r;
#pragma unroll
            for (int fc = 0; fc < 4; ++fc) {
                const int gj = j0 + wc * 64 + fc * 16 + l15;
                Sh[(size_t)gi * NN + gj] = acc[fr][fc][r];
            }
        }
}

// ---------------------------------------------------------------------------
// softmax: read S fp32 row, write A bf16 row. grid CH*NN blocks of 256.
// ---------------------------------------------------------------------------
__global__ __launch_bounds__(256) void softmax_b(
    const float* __restrict__ Sb, u16* __restrict__ Abf)
{
    const int row = blockIdx.x;
    const float* p = Sb + (size_t)row * NN;
    u16* q = Abf + (size_t)row * NN;
    const int tid = threadIdx.x;
    __shared__ float redm[4], reds[4];

    float4 v = *(const float4*)&p[tid * 4];
    float m = fmaxf(fmaxf(v.x, v.y), fmaxf(v.z, v.w));
#pragma unroll
    for (int off = 32; off >= 1; off >>= 1) m = fmaxf(m, __shfl_xor(m, off));
    if ((tid & 63) == 0) redm[tid >> 6] = m;
    __syncthreads();
    m = fmaxf(fmaxf(redm[0], redm[1]), fmaxf(redm[2], redm[3]));

    v.x = expf(v.x - m); v.y = expf(v.y - m);
    v.z = expf(v.z - m); v.w = expf(v.w - m);
    float s = v.x + v.y + v.z + v.w;
#pragma unroll
    for (int off = 32; off >= 1; off >>= 1) s += __shfl_xor(s, off);
    if ((tid & 63) == 0) reds[tid >> 6] = s;
    __syncthreads();
    s = reds[0] + reds[1] + reds[2] + reds[3];

    const float inv = 1.0f / s;
    u16x4 o;
    o[0] = f2bf(v.x * inv); o[1] = f2bf(v.y * inv);
    o[2] = f2bf(v.z * inv); o[3] = f2bf(v.w * inv);
    *(u16x4*)&q[tid * 4] = o;
}

// ---------------------------------------------------------------------------
// mpow: P = A@A (bf16 MFMA); M = relu(del*I + c1*A + c2*P) -> bf16.
// B-operand staged by in-kernel transpose of A's k-rows (no At buffer).
// grid (8, 8, CH), 128x128 tile, BK=32. XCD swizzle: one head per XCD run.
// ---------------------------------------------------------------------------
__global__ __launch_bounds__(256) void mpow_mfma(
    const u16* __restrict__ Abf, u16* __restrict__ Mb,
    const float* __restrict__ lamb, const float* __restrict__ gamma,
    const float* __restrict__ delta, int h0)
{
    __shared__ alignas(16) u16 sA[128 * 32], sB[128 * 32];
    const int tid = threadIdx.x;
    const int W = swz_linear();
    const int bz = W >> 6;
    const int ib = W & 63;
    const int j0 = (ib & 7) * 128, i0 = (ib >> 3) * 128;
    const int h = (h0 + bz) % NH;
    const u16* Ah = Abf + (size_t)bz * NN * NN;

    const int w = tid >> 6, l = tid & 63;
    const int wr = w >> 1, wc = w & 1;
    const int l15 = l & 15, kb4 = l >> 4;
    const int lrow = l >> 2, lch = (l & 3) * 8;
    // B transpose staging map: 256 threads cover 32 k-rows x 128 j-cols
    const int kr = tid & 31;
    const int jc = (tid >> 5) * 16;

    f32x4 acc[4][4];
    const f32x4 zero = {0.f, 0.f, 0.f, 0.f};
#pragma unroll
    for (int a = 0; a < 4; ++a)
#pragma unroll
        for (int b = 0; b < 4; ++b) acc[a][b] = zero;

    for (int k0 = 0; k0 < NN; k0 += 32) {
        // A-side: async direct to LDS
#pragma unroll
        for (int t = 0; t < 2; ++t) {
            const int r = w * 32 + t * 16;
            GLD16(&Ah[(size_t)(i0 + r + lrow) * NN + k0 + lch], &sA[r * 32]);
        }
        // B-side: read A's k-rows (coalesced), write transposed [j][k]
        {
            const u16* arow = &Ah[(size_t)(k0 + kr) * NN + j0 + jc];
            u16x8 b0 = *(const u16x8*)arow;
            u16x8 b1 = *(const u16x8*)(arow + 8);
#pragma unroll
            for (int e = 0; e < 8; ++e) {
                sB[(jc + e) * 32 + kr]     = b0[e];
                sB[(jc + 8 + e) * 32 + kr] = b1[e];
            }
        }
        __syncthreads();

        s16x8 af[4], bf[4];
#pragma unroll
        for (int f = 0; f < 4; ++f) {
            af[f] = *(const s16x8*)&sA[(wr * 64 + f * 16 + l15) * 32 + kb4 * 8];
            bf[f] = *(const s16x8*)&sB[(wc * 64 + f * 16 + l15) * 32 + kb4 * 8];
        }
#pragma unroll
        for (int fr = 0; fr < 4; ++fr)
#pragma unroll
            for (int fc = 0; fc < 4; ++fc)
                acc[fr][fc] = __builtin_amdgcn_mfma_f32_16x16x32_bf16(
                    af[fr], bf[fc], acc[fr][fc], 0, 0, 0);
        __syncthreads();
    }

    const float lam = lamb[h];
    const float c1 = gamma[h] - 6.0f * lam;
    const float c2 = 7.0f * lam;
    const float del = delta[h];
    u16* Mh = Mb + (size_t)bz * NN * NN;

#pragma unroll
    for (int fr = 0; fr < 4; ++fr)
#pragma unroll
        for (int r = 0; r < 4; ++r) {
            const int gi = i0 + wr * 64 + fr * 16 + kb4 * 4 + r;
#pragma unroll
            for (int fc = 0; fc < 4; ++fc) {
                const int gj = j0 + wc * 64 + fc * 16 + l15;
                const float a = bf2f(Ah[(size_t)gi * NN + gj]);
                float m = c2 * acc[fr][fc][r] + c1 * a + (gi == gj ? del : 0.f);
                m = fmaxf(m, 0.f);
                Mh[(size_t)gi * NN + gj] = f2bf(m);
            }
        }
}

// ---------------------------------------------------------------------------
// pv: ao = (M @ V) / rowsum(M). V as v^T hi/lo (2-term split); rowsum via
// ones-fragment MFMA. grid (8 i-tiles, CH). XCD swizzle.
// ---------------------------------------------------------------------------
__global__ __launch_bounds__(256) void pv_mfma(
    const u16* __restrict__ Mb,
    const u16* __restrict__ vth, const u16* __restrict__ vtl,
    u16* __restrict__ aoh, u16* __restrict__ aol, int h0)
{
    __shared__ alignas(16) u16 sM[128 * 32], sVh[64 * 32], sVl[64 * 32];
    const int tid = threadIdx.x;
    const int W = swz_linear();
    const int bhl = W >> 3;
    const int i0 = (W & 7) * 128;
    const int bh = h0 + bhl;
    const int b = bh / NH, h = bh % NH;
    const u16* Mh = Mb + (size_t)bhl * NN * NN;
    const u16* vhb = vth + (size_t)bh * HD * NN;
    const u16* vlb = vtl + (size_t)bh * HD * NN;

    const int w = tid >> 6, l = tid & 63;
    const int l15 = l & 15, kb4 = l >> 4;
    const int lrow = l >> 2, lch = (l & 3) * 8;

    f32x4 acc[2][4], accs[2];
    const f32x4 zero = {0.f, 0.f, 0.f, 0.f};
#pragma unroll
    for (int a = 0; a < 2; ++a) {
#pragma unroll
        for (int c = 0; c < 4; ++c) acc[a][c] = zero;
        accs[a] = zero;
    }
    s16x8 ones;
#pragma unroll
    for (int e = 0; e < 8; ++e) ones[e] = (short)0x3F80;   // bf16 1.0

    for (int k0 = 0; k0 < NN; k0 += 32) {
#pragma unroll
        for (int t = 0; t < 2; ++t) {
            const int r = w * 32 + t * 16;
            GLD16(&Mh[(size_t)(i0 + r + lrow) * NN + k0 + lch], &sM[r * 32]);
        }
        {
            const int r = w * 16;                  // V rows: 4 waves x 16 = 64
            const size_t vr = (size_t)(r + lrow) * NN + k0 + lch;
            GLD16(&vhb[vr], &sVh[r * 32]);
            GLD16(&vlb[vr], &sVl[r * 32]);
        }
        __syncthreads();

        s16x8 af[2], bh[4], bl[4];
#pragma unroll
        for (int f = 0; f < 2; ++f)
            af[f] = *(const s16x8*)&sM[(w * 32 + f * 16 + l15) * 32 + kb4 * 8];
#pragma unroll
        for (int f = 0; f < 4; ++f) {
            bh[f] = *(const s16x8*)&sVh[(f * 16 + l15) * 32 + kb4 * 8];
            bl[f] = *(const s16x8*)&sVl[(f * 16 + l15) * 32 + kb4 * 8];
        }
#pragma unroll
        for (int fr = 0; fr < 2; ++fr) {
#pragma unroll
            for (int fc = 0; fc < 4; ++fc) {
                acc[fr][fc] = __builtin_amdgcn_mfma_f32_16x16x32_bf16(
                    af[fr], bh[fc], acc[fr][fc], 0, 0, 0);
                acc[fr][fc] = __builtin_amdgcn_mfma_f32_16x16x32_bf16(
                    af[fr], bl[fc], acc[fr][fc], 0, 0, 0);
            }
            accs[fr] = __builtin_amdgcn_mfma_f32_16x16x32_bf16(
                af[fr], ones, accs[fr], 0, 0, 0);
        }
        __syncthreads();
    }

#pragma unroll
    for (int fr = 0; fr < 2; ++fr)
#pragma unroll
        for (int r = 0; r < 4; ++r) {
            const int gi = i0 + w * 32 + fr * 16 + kb4 * 4 + r;
            const float inv = 1.0f / (accs[fr][r] + 1e-9f);
            const size_t ob = (size_t)(b * NN + gi) * DIMC + h * HD;
#pragma unroll
            for (int fc = 0; fc < 4; ++fc) {
                const int gd = fc * 16 + l15;
                bfp s = splitf(acc[fr][fc][r] * inv);
                aoh[ob + gd] = s.h;
                aol[ob + gd] = s.l;
            }
        }
}

// ---------------------------------------------------------------------------
extern "C" void kernel_launch(void* const* d_in, const int* in_sizes, int n_in,
                              void* d_out, int out_size, void* d_ws, size_t ws_size,
                              hipStream_t stream)
{
    const float* x      = (const float*)d_in[0];
    const float* qkv_w  = (const float*)d_in[1];
    const float* qkv_b  = (const float*)d_in[2];
    const float* proj_w = (const float*)d_in[3];
    const float* proj_b = (const float*)d_in[4];
    const float* lamb   = (const float*)d_in[5];
    const float* gamma  = (const float*)d_in[6];
    const float* delta  = (const float*)d_in[7];

    char* p = (char*)d_ws;
    u16* xh  = (u16*)p;                     p += (size_t)4096 * DIMC * 2;
    u16* xl  = (u16*)p;                     p += (size_t)4096 * DIMC * 2;
    u16* wh  = (u16*)p;                     p += (size_t)QKVC * DIMC * 2;
    u16* wl  = (u16*)p;                     p += (size_t)QKVC * DIMC * 2;
    u16* pwh = (u16*)p;                     p += (size_t)DIMC * DIMC * 2;
    u16* pwl = (u16*)p;                     p += (size_t)DIMC * DIMC * 2;
    u16* qh  = (u16*)p;                     p += (size_t)BHT * NN * HD * 2;
    u16* ql  = (u16*)p;                     p += (size_t)BHT * NN * HD * 2;
    u16* kh  = (u16*)p;                     p += (size_t)BHT * NN * HD * 2;
    u16* kl  = (u16*)p;                     p += (size_t)BHT * NN * HD * 2;
    u16* vth = (u16*)p;                     p += (size_t)BHT * HD * NN * 2;
    u16* vtl = (u16*)p;                     p += (size_t)BHT * HD * NN * 2;
    u16* aoh = (u16*)p;                     p += (size_t)4096 * DIMC * 2;
    u16* aol = (u16*)p;                     p += (size_t)4096 * DIMC * 2;
    const size_t fixed = (size_t)(p - (char*)d_ws);

    // per-head: S fp32 4MB (M bf16 aliases into it) + A bf16 2MB
    const size_t perh = (size_t)NN * NN * 4 + (size_t)NN * NN * 2;
    static const int choices[] = {48, 24, 16, 12, 8, 6, 4, 3, 2, 1};
    int CH = 1;
    for (int ci = 0; ci < 10; ++ci) {
        int c = choices[ci];
        if (fixed + (size_t)c * perh <= ws_size) { CH = c; break; }
    }

    float* Sb = (float*)p;                  p += (size_t)CH * NN * NN * 4;
    u16* Abf  = (u16*)p;                    p += (size_t)CH * NN * NN * 2;
    u16* Mb   = (u16*)Sb;                   // alias: S dead after softmax

    // 0) splits of inputs
    split_f2b<<<dim3((4096 * DIMC / 4 + 255) / 256), 256, 0, stream>>>(x, xh, xl, 4096 * DIMC / 4);
    split_f2b<<<dim3((QKVC * DIMC / 4 + 255) / 256), 256, 0, stream>>>(qkv_w, wh, wl, QKVC * DIMC / 4);
    split_f2b<<<dim3((DIMC * DIMC / 4 + 255) / 256), 256, 0, stream>>>(proj_w, pwh, pwl, DIMC * DIMC / 4);

    // 1) qkv GEMM fused: writes qh/ql/kh/kl (bh,n,64) and vth/vtl (bh,64,n)
    qkv_fused_mfma<<<dim3(QKVC / 128, 4096 / 128), 256, 0, stream>>>(
        xh, xl, wh, wl, qkv_b, qh, ql, kh, kl, vth, vtl);

    // 2..5) per chunk of heads
    for (int h0 = 0; h0 < BHT; h0 += CH) {
        qk_mfma<<<dim3(8, 8, CH), 256, 0, stream>>>(qh, ql, kh, kl, Sb, h0);
        softmax_b<<<dim3(CH * NN), 256, 0, stream>>>(Sb, Abf);
        mpow_mfma<<<dim3(8, 8, CH), 256, 0, stream>>>(
            Abf, Mb, lamb, gamma, delta, h0);
        pv_mfma<<<dim3(8, CH), 256, 0, stream>>>(Mb, vth, vtl, aoh, aol, h0);
    }

    // 6) final = ao @ proj_w^T + proj_b
    gemm3_mfma<<<dim3(DIMC / 128, 4096 / 128), 256, 0, stream>>>(
        4096, DIMC, DIMC, aoh, aol, pwh, pwl, proj_b, (float*)d_out);
}